// Round 1
// baseline (352.355 us; speedup 1.0000x reference)
//
#include <hip/hip_runtime.h>

#define NEG 0.2f

// order-preserving float<->uint mapping for atomicMax on floats
__device__ __forceinline__ unsigned fmap(float f){
    unsigned b = __float_as_uint(f);
    return (b & 0x80000000u) ? ~b : (b | 0x80000000u);
}
__device__ __forceinline__ float funmap(unsigned u){
    return (u & 0x80000000u) ? __uint_as_float(u & 0x7fffffffu) : __uint_as_float(~u);
}

// per-head GATv2 logit from 3 scalars; weight indices are compile-time after
// unroll and pointers are uniform kernel args -> compiler emits scalar loads.
__device__ __forceinline__ float head_logit(float xs, float xd, float a,
                                            const float* __restrict__ Wl,
                                            const float* __restrict__ Wr,
                                            const float* __restrict__ We,
                                            const float* __restrict__ bsum,
                                            const float* __restrict__ att,
                                            int h){
    float acc = 0.f;
    const int base = h * 64;
    #pragma unroll
    for (int c = 0; c < 64; ++c){
        const int hc = base + c;
        float v = fmaf(xs, Wl[hc], fmaf(xd, Wr[hc], fmaf(a, We[hc], bsum[hc])));
        float g = fmaxf(v, NEG * v);          // leaky_relu, slope<1
        acc = fmaf(g, att[hc], acc);
    }
    return acc;
}

__global__ void k_prep(const float* __restrict__ bl, const float* __restrict__ br,
                       float* __restrict__ bsum){
    int t = threadIdx.x;
    if (t < 128) bsum[t] = bl[t] + br[t];
}

// scatter edge_attr sum + indegree count per destination (for self-loop 'mean')
__global__ void k_scatter_attr(const int* __restrict__ dst,
                               const float* __restrict__ attr,
                               float* __restrict__ attr_sum,
                               float* __restrict__ cnt, int E){
    int e = blockIdx.x * 256 + threadIdx.x;
    if (e >= E) return;
    int d = dst[e];
    atomicAdd(&attr_sum[d], attr[e]);
    atomicAdd(&cnt[d], 1.0f);
}

// per-node self-loop logit; initializes segment max (every node has exactly
// one self loop, so no atomic needed here)
__global__ void k_loop(const float* __restrict__ x,
                       const float* __restrict__ attr_sum,
                       const float* __restrict__ cnt,
                       const float* __restrict__ Wl, const float* __restrict__ Wr,
                       const float* __restrict__ We, const float* __restrict__ bsum,
                       const float* __restrict__ att,
                       float* __restrict__ logit_loop, unsigned* __restrict__ maxu,
                       int N){
    int node = blockIdx.x * 256 + threadIdx.x;
    if (node >= N) return;
    float xi = x[node];
    float la = attr_sum[node] / fmaxf(cnt[node], 1.0f);
    float l0 = head_logit(xi, xi, la, Wl, Wr, We, bsum, att, 0);
    float l1 = head_logit(xi, xi, la, Wl, Wr, We, bsum, att, 1);
    logit_loop[2*node]   = l0;
    logit_loop[2*node+1] = l1;
    maxu[2*node]   = fmap(l0);
    maxu[2*node+1] = fmap(l1);
}

// pass 1 over edges: logits -> segment max via atomicMax
__global__ void k_edge_max(const int* __restrict__ src, const int* __restrict__ dst,
                           const float* __restrict__ attr, const float* __restrict__ x,
                           const float* __restrict__ Wl, const float* __restrict__ Wr,
                           const float* __restrict__ We, const float* __restrict__ bsum,
                           const float* __restrict__ att,
                           unsigned* __restrict__ maxu, int E){
    int e = blockIdx.x * 256 + threadIdx.x;
    if (e >= E) return;
    int s = src[e], d = dst[e];
    float xs = x[s], xd = x[d], a = attr[e];
    float l0 = head_logit(xs, xd, a, Wl, Wr, We, bsum, att, 0);
    float l1 = head_logit(xs, xd, a, Wl, Wr, We, bsum, att, 1);
    atomicMax(&maxu[2*d],   fmap(l0));
    atomicMax(&maxu[2*d+1], fmap(l1));
}

// pass 2 over edges: p = exp(l - max); accumulate denom and weighted numerator
__global__ void k_edge_sum(const int* __restrict__ src, const int* __restrict__ dst,
                           const float* __restrict__ attr, const float* __restrict__ x,
                           const float* __restrict__ Wl, const float* __restrict__ Wr,
                           const float* __restrict__ We, const float* __restrict__ bsum,
                           const float* __restrict__ att,
                           const unsigned* __restrict__ maxu,
                           float* __restrict__ denom, float* __restrict__ nums, int E){
    int e = blockIdx.x * 256 + threadIdx.x;
    if (e >= E) return;
    int s = src[e], d = dst[e];
    float xs = x[s], xd = x[d], a = attr[e];
    float l0 = head_logit(xs, xd, a, Wl, Wr, We, bsum, att, 0);
    float l1 = head_logit(xs, xd, a, Wl, Wr, We, bsum, att, 1);
    float p0 = expf(l0 - funmap(maxu[2*d]));
    float p1 = expf(l1 - funmap(maxu[2*d+1]));
    atomicAdd(&denom[2*d],   p0);
    atomicAdd(&nums[2*d],    p0 * xs);
    atomicAdd(&denom[2*d+1], p1);
    atomicAdd(&nums[2*d+1],  p1 * xs);
}

// finalize: add self-loop contribution, divide, rank-1 expand, write out
__global__ void k_final(const float* __restrict__ x,
                        const float* __restrict__ logit_loop,
                        const unsigned* __restrict__ maxu,
                        const float* __restrict__ denom, const float* __restrict__ nums,
                        const float* __restrict__ Wl, const float* __restrict__ bl,
                        const float* __restrict__ bias,
                        float* __restrict__ out, int N){
    int t = blockIdx.x * 256 + threadIdx.x;
    if (t >= N * 128) return;
    int i  = t >> 7;
    int hc = t & 127;
    int h  = hc >> 6;
    int ih = 2*i + h;
    float m   = funmap(maxu[ih]);
    float el  = expf(logit_loop[ih] - m);     // self-loop term (m >= loop logit)
    float den = denom[ih] + el;
    float num = fmaf(el, x[i], nums[ih]);
    float sres = num / den;
    out[t] = fmaf(sres, Wl[hc], bl[hc] + bias[hc]);
}

extern "C" void kernel_launch(void* const* d_in, const int* in_sizes, int n_in,
                              void* d_out, int out_size, void* d_ws, size_t ws_size,
                              hipStream_t stream) {
    const float* x    = (const float*)d_in[0];
    const int*   ei   = (const int*)  d_in[1];
    const float* attr = (const float*)d_in[2];
    const float* Wl   = (const float*)d_in[3];
    const float* bl   = (const float*)d_in[4];
    const float* Wr   = (const float*)d_in[5];
    const float* br   = (const float*)d_in[6];
    const float* We   = (const float*)d_in[7];
    const float* att  = (const float*)d_in[8];
    const float* bias = (const float*)d_in[9];
    float* out = (float*)d_out;

    const int N = in_sizes[0];       // 50000
    const int E = in_sizes[2];       // 800000
    const int* src = ei;
    const int* dst = ei + E;

    float* ws = (float*)d_ws;
    float*    attr_sum   = ws;                       // [N]
    float*    cnt        = ws + N;                   // [N]
    float*    denom      = ws + 2*(size_t)N;         // [2N]
    float*    nums       = ws + 4*(size_t)N;         // [2N]
    float*    logit_loop = ws + 6*(size_t)N;         // [2N]
    unsigned* maxu       = (unsigned*)(ws + 8*(size_t)N); // [2N]
    float*    bsum       = ws + 10*(size_t)N;        // [128]

    // zero attr_sum, cnt, denom, nums (contiguous 6N floats)
    hipMemsetAsync(ws, 0, (size_t)6 * N * sizeof(float), stream);

    k_prep<<<1, 128, 0, stream>>>(bl, br, bsum);
    k_scatter_attr<<<(E + 255) / 256, 256, 0, stream>>>(dst, attr, attr_sum, cnt, E);
    k_loop<<<(N + 255) / 256, 256, 0, stream>>>(x, attr_sum, cnt, Wl, Wr, We, bsum, att,
                                                logit_loop, maxu, N);
    k_edge_max<<<(E + 255) / 256, 256, 0, stream>>>(src, dst, attr, x, Wl, Wr, We, bsum, att,
                                                    maxu, E);
    k_edge_sum<<<(E + 255) / 256, 256, 0, stream>>>(src, dst, attr, x, Wl, Wr, We, bsum, att,
                                                    maxu, denom, nums, E);
    k_final<<<((size_t)N * 128 + 255) / 256, 256, 0, stream>>>(x, logit_loop, maxu, denom, nums,
                                                               Wl, bl, bias, out, N);
}

// Round 2
// 227.001 us; speedup vs baseline: 1.5522x; 1.5522x over previous
//
#include <hip/hip_runtime.h>

#define NEG 0.2f

// per-head GATv2 logit from 3 scalars; weights are wave-uniform -> scalar loads
__device__ __forceinline__ float head_logit(float xs, float xd, float a,
                                            const float* __restrict__ Wl,
                                            const float* __restrict__ Wr,
                                            const float* __restrict__ We,
                                            const float* __restrict__ bsum,
                                            const float* __restrict__ att,
                                            int h){
    float acc = 0.f;
    const int base = h * 64;
    #pragma unroll
    for (int c = 0; c < 64; ++c){
        const int hc = base + c;
        float v = fmaf(xs, Wl[hc], fmaf(xd, Wr[hc], fmaf(a, We[hc], bsum[hc])));
        float g = fmaxf(v, NEG * v);          // leaky_relu, slope < 1
        acc = fmaf(g, att[hc], acc);
    }
    return acc;
}

// indegree histogram (the only atomics besides the scatter cursor)
__global__ void k_count(const int* __restrict__ dst, int* __restrict__ cnt, int E){
    int e = blockIdx.x * 256 + threadIdx.x;
    if (e < E) atomicAdd(&cnt[dst[e]], 1);
}

// single-block exclusive prefix sum over cnt[N] -> offsets, cursor; fused bsum prep
__global__ void k_scan(const int* __restrict__ cnt, int* __restrict__ offsets,
                       int* __restrict__ cursor,
                       const float* __restrict__ bl, const float* __restrict__ br,
                       float* __restrict__ bsum, int N){
    __shared__ int part[1024];
    int t = threadIdx.x;
    if (t < 128) bsum[t] = bl[t] + br[t];
    int chunk = (N + 1023) >> 10;
    int lo = t * chunk, hi = min(lo + chunk, N);
    if (lo > N) lo = N;
    int s = 0;
    for (int i = lo; i < hi; ++i) s += cnt[i];
    part[t] = s;
    __syncthreads();
    for (int off = 1; off < 1024; off <<= 1){
        int v = (t >= off) ? part[t - off] : 0;
        __syncthreads();
        part[t] += v;
        __syncthreads();
    }
    int base = (t > 0) ? part[t - 1] : 0;
    for (int i = lo; i < hi; ++i){ offsets[i] = base; cursor[i] = base; base += cnt[i]; }
    if (t == 1023) offsets[N] = part[1023];
}

// per edge: compute both head logits, then scatter payload into CSR slot
__global__ void k_scatter(const int* __restrict__ src, const int* __restrict__ dst,
                          const float* __restrict__ attr, const float* __restrict__ x,
                          const float* __restrict__ Wl, const float* __restrict__ Wr,
                          const float* __restrict__ We, const float* __restrict__ bsum,
                          const float* __restrict__ att,
                          int* __restrict__ cursor, float4* __restrict__ sorted, int E){
    int e = blockIdx.x * 256 + threadIdx.x;
    if (e >= E) return;
    int s = src[e], d = dst[e];
    float xs = x[s], xd = x[d], a = attr[e];
    float l0 = head_logit(xs, xd, a, Wl, Wr, We, bsum, att, 0);
    float l1 = head_logit(xs, xd, a, Wl, Wr, We, bsum, att, 1);
    int pos = atomicAdd(&cursor[d], 1);
    sorted[pos] = make_float4(xs, a, l0, l1);
}

// per node: exact online softmax over its contiguous edges + self-loop, no atomics
__global__ void k_node(const float* __restrict__ x,
                       const int* __restrict__ offsets,
                       const float4* __restrict__ sorted,
                       const float* __restrict__ Wl, const float* __restrict__ Wr,
                       const float* __restrict__ We, const float* __restrict__ bsum,
                       const float* __restrict__ att,
                       float* __restrict__ sres, int N){
    int i = blockIdx.x * 256 + threadIdx.x;
    if (i >= N) return;
    int st = offsets[i], en = offsets[i + 1];
    float m0 = -3.4e38f, d0 = 0.f, n0 = 0.f;
    float m1 = -3.4e38f, d1 = 0.f, n1 = 0.f;
    float asum = 0.f;
    for (int p = st; p < en; ++p){
        float4 v = sorted[p];                 // (xs, a, l0, l1)
        asum += v.y;
        float mn0 = fmaxf(m0, v.z);
        float s0 = expf(m0 - mn0);
        float p0 = expf(v.z - mn0);
        d0 = fmaf(d0, s0, p0);
        n0 = fmaf(n0, s0, p0 * v.x);
        m0 = mn0;
        float mn1 = fmaxf(m1, v.w);
        float s1 = expf(m1 - mn1);
        float p1 = expf(v.w - mn1);
        d1 = fmaf(d1, s1, p1);
        n1 = fmaf(n1, s1, p1 * v.x);
        m1 = mn1;
    }
    // self-loop: edge_attr = mean of incoming attr (0 if none), src = dst = i
    float xi = x[i];
    int deg = en - st;
    float la = asum / (float)max(deg, 1);
    float l0 = head_logit(xi, xi, la, Wl, Wr, We, bsum, att, 0);
    float l1 = head_logit(xi, xi, la, Wl, Wr, We, bsum, att, 1);
    {
        float mn = fmaxf(m0, l0);
        float s0 = expf(m0 - mn), p0 = expf(l0 - mn);
        d0 = fmaf(d0, s0, p0);
        n0 = fmaf(n0, s0, p0 * xi);
    }
    {
        float mn = fmaxf(m1, l1);
        float s1 = expf(m1 - mn), p1 = expf(l1 - mn);
        d1 = fmaf(d1, s1, p1);
        n1 = fmaf(n1, s1, p1 * xi);
    }
    sres[2 * i]     = n0 / d0;
    sres[2 * i + 1] = n1 / d1;
}

// rank-1 expansion: out[i, h*64+c] = sres[i,h] * Wl[h*64+c] + bl + bias
__global__ void k_final(const float* __restrict__ sres,
                        const float* __restrict__ Wl, const float* __restrict__ bl,
                        const float* __restrict__ bias,
                        float* __restrict__ out, int total){
    int t = blockIdx.x * 256 + threadIdx.x;
    if (t >= total) return;
    int i  = t >> 7;
    int hc = t & 127;
    int h  = hc >> 6;
    out[t] = fmaf(sres[2 * i + h], Wl[hc], bl[hc] + bias[hc]);
}

extern "C" void kernel_launch(void* const* d_in, const int* in_sizes, int n_in,
                              void* d_out, int out_size, void* d_ws, size_t ws_size,
                              hipStream_t stream) {
    const float* x    = (const float*)d_in[0];
    const int*   ei   = (const int*)  d_in[1];
    const float* attr = (const float*)d_in[2];
    const float* Wl   = (const float*)d_in[3];
    const float* bl   = (const float*)d_in[4];
    const float* Wr   = (const float*)d_in[5];
    const float* br   = (const float*)d_in[6];
    const float* We   = (const float*)d_in[7];
    const float* att  = (const float*)d_in[8];
    const float* bias = (const float*)d_in[9];
    float* out = (float*)d_out;

    const int N = in_sizes[0];       // 50000
    const int E = in_sizes[2];       // 800000
    const int* src = ei;
    const int* dst = ei + E;

    // workspace layout (descending alignment): sorted must be 16B aligned
    char* w = (char*)d_ws;
    float4* sorted  = (float4*)w;                          // E * 16B = 12.8 MB
    float*  sres    = (float*)(w + (size_t)E * 16);        // 2N floats
    float*  bsum    = sres + 2 * (size_t)N;                // 128 floats
    int*    cnt     = (int*)(bsum + 128);                  // N ints
    int*    offsets = cnt + N;                             // N+1 ints
    int*    cursor  = offsets + N + 1;                     // N ints

    hipMemsetAsync(cnt, 0, (size_t)N * sizeof(int), stream);

    k_count<<<(E + 255) / 256, 256, 0, stream>>>(dst, cnt, E);
    k_scan<<<1, 1024, 0, stream>>>(cnt, offsets, cursor, bl, br, bsum, N);
    k_scatter<<<(E + 255) / 256, 256, 0, stream>>>(src, dst, attr, x,
                                                   Wl, Wr, We, bsum, att,
                                                   cursor, sorted, E);
    k_node<<<(N + 255) / 256, 256, 0, stream>>>(x, offsets, sorted,
                                                Wl, Wr, We, bsum, att, sres, N);
    k_final<<<((size_t)N * 128 + 255) / 256, 256, 0, stream>>>(sres, Wl, bl, bias,
                                                               out, N * 128);
}

// Round 3
// 103.555 us; speedup vs baseline: 3.4026x; 2.1921x over previous
//
#include <hip/hip_runtime.h>

#define NEG 0.2f
#define MAXDEG 64

// per-head GATv2 logit from 3 scalars; weights are wave-uniform -> scalar loads
__device__ __forceinline__ float head_logit(float xs, float xd, float a,
                                            const float* __restrict__ Wl,
                                            const float* __restrict__ Wr,
                                            const float* __restrict__ We,
                                            const float* __restrict__ bsum,
                                            const float* __restrict__ att,
                                            int h){
    float acc = 0.f;
    const int base = h * 64;
    #pragma unroll
    for (int c = 0; c < 64; ++c){
        const int hc = base + c;
        float v = fmaf(xs, Wl[hc], fmaf(xd, Wr[hc], fmaf(a, We[hc], bsum[hc])));
        float g = fmaxf(v, NEG * v);          // leaky_relu, slope < 1
        acc = fmaf(g, att[hc], acc);
    }
    return acc;
}

__global__ void k_prep(const float* __restrict__ bl, const float* __restrict__ br,
                       const float* __restrict__ bias,
                       float* __restrict__ bsum, float* __restrict__ bb){
    int t = threadIdx.x;
    if (t < 128){ bsum[t] = bl[t] + br[t]; bb[t] = bl[t] + bias[t]; }
}

// ---------------- fast path: single edge pass, padded-slot CSR ----------------

__global__ void k_edge(const int* __restrict__ src, const int* __restrict__ dst,
                       const float* __restrict__ attr, const float* __restrict__ x,
                       const float* __restrict__ Wl, const float* __restrict__ Wr,
                       const float* __restrict__ We, const float* __restrict__ bsum,
                       const float* __restrict__ att,
                       int* __restrict__ deg, int* __restrict__ slot,
                       float4* __restrict__ payload, int E){
    int e = blockIdx.x * 256 + threadIdx.x;
    if (e >= E) return;
    int s = src[e], d = dst[e];
    float xs = x[s], xd = x[d], a = attr[e];
    float l0 = head_logit(xs, xd, a, Wl, Wr, We, bsum, att, 0);
    float l1 = head_logit(xs, xd, a, Wl, Wr, We, bsum, att, 1);
    payload[e] = make_float4(xs, a, l0, l1);          // coalesced
    int pos = atomicAdd(&deg[d], 1);
    if (pos < MAXDEG) slot[(d << 6) + pos] = e;       // scattered 4B
}

// 4 lanes per node: strided slot walk + shfl merge of online-softmax partials
__global__ void k_node4(const float* __restrict__ x,
                        const int* __restrict__ deg, const int* __restrict__ slot,
                        const float4* __restrict__ payload,
                        const float* __restrict__ Wl, const float* __restrict__ Wr,
                        const float* __restrict__ We, const float* __restrict__ bsum,
                        const float* __restrict__ att,
                        float* __restrict__ sres, int N){
    int t = blockIdx.x * 256 + threadIdx.x;
    int i = t >> 2, sub = t & 3;
    bool valid = i < N;
    int dall = valid ? deg[i] : 0;
    int dg = min(dall, MAXDEG);
    float m0 = -3.4e38f, d0 = 0.f, n0 = 0.f;
    float m1 = -3.4e38f, d1 = 0.f, n1 = 0.f;
    float asum = 0.f;
    for (int p = sub; p < dg; p += 4){
        int e = slot[(i << 6) + p];
        float4 v = payload[e];                 // (xs, a, l0, l1)
        asum += v.y;
        float mn0 = fmaxf(m0, v.z);
        float s0 = expf(m0 - mn0), p0 = expf(v.z - mn0);
        d0 = fmaf(d0, s0, p0);
        n0 = fmaf(n0, s0, p0 * v.x);
        m0 = mn0;
        float mn1 = fmaxf(m1, v.w);
        float s1 = expf(m1 - mn1), p1 = expf(v.w - mn1);
        d1 = fmaf(d1, s1, p1);
        n1 = fmaf(n1, s1, p1 * v.x);
        m1 = mn1;
    }
    // merge partials across the 4 lanes of this node
    #pragma unroll
    for (int off = 1; off < 4; off <<= 1){
        float om0 = __shfl_xor(m0, off), od0 = __shfl_xor(d0, off), on0 = __shfl_xor(n0, off);
        float om1 = __shfl_xor(m1, off), od1 = __shfl_xor(d1, off), on1 = __shfl_xor(n1, off);
        asum += __shfl_xor(asum, off);
        float mn = fmaxf(m0, om0);
        d0 = d0 * expf(m0 - mn) + od0 * expf(om0 - mn);
        n0 = n0 * expf(m0 - mn) + on0 * expf(om0 - mn);
        m0 = mn;
        mn = fmaxf(m1, om1);
        d1 = d1 * expf(m1 - mn) + od1 * expf(om1 - mn);
        n1 = n1 * expf(m1 - mn) + on1 * expf(om1 - mn);
        m1 = mn;
    }
    // self-loop: attr = mean of incoming (0 if none), src = dst = i
    float xi = valid ? x[i] : 0.f;
    float la = asum / (float)max(dall, 1);
    float l0 = head_logit(xi, xi, la, Wl, Wr, We, bsum, att, 0);
    float l1 = head_logit(xi, xi, la, Wl, Wr, We, bsum, att, 1);
    {
        float mn = fmaxf(m0, l0);
        float s = expf(m0 - mn), p = expf(l0 - mn);
        d0 = fmaf(d0, s, p);
        n0 = fmaf(n0, s, p * xi);
    }
    {
        float mn = fmaxf(m1, l1);
        float s = expf(m1 - mn), p = expf(l1 - mn);
        d1 = fmaf(d1, s, p);
        n1 = fmaf(n1, s, p * xi);
    }
    if (valid && sub == 0){
        sres[2 * i]     = n0 / d0;
        sres[2 * i + 1] = n1 / d1;
    }
}

// rank-1 expansion, float4-vectorized: out[i,hc] = sres[i,h]*Wl[hc] + (bl+bias)[hc]
__global__ void k_final4(const float* __restrict__ sres,
                         const float* __restrict__ Wl, const float* __restrict__ bb,
                         float4* __restrict__ out, int total4){
    int t = blockIdx.x * 256 + threadIdx.x;
    if (t >= total4) return;
    int i = t >> 5;
    int q = t & 31;        // float4 index within the 128-wide row
    int h = q >> 4;
    float s = sres[2 * i + h];
    float4 wv = ((const float4*)Wl)[q];
    float4 bv = ((const float4*)bb)[q];
    out[t] = make_float4(fmaf(s, wv.x, bv.x), fmaf(s, wv.y, bv.y),
                         fmaf(s, wv.z, bv.z), fmaf(s, wv.w, bv.w));
}

// ---------------- fallback path (ws too small): round-2 structure ----------------

__global__ void k_count(const int* __restrict__ dst, int* __restrict__ cnt, int E){
    int e = blockIdx.x * 256 + threadIdx.x;
    if (e < E) atomicAdd(&cnt[dst[e]], 1);
}

__global__ void k_scan(const int* __restrict__ cnt, int* __restrict__ offsets,
                       int* __restrict__ cursor, int N){
    __shared__ int part[1024];
    int t = threadIdx.x;
    int chunk = (N + 1023) >> 10;
    int lo = t * chunk, hi = min(lo + chunk, N);
    if (lo > N) lo = N;
    int s = 0;
    for (int i = lo; i < hi; ++i) s += cnt[i];
    part[t] = s;
    __syncthreads();
    for (int off = 1; off < 1024; off <<= 1){
        int v = (t >= off) ? part[t - off] : 0;
        __syncthreads();
        part[t] += v;
        __syncthreads();
    }
    int base = (t > 0) ? part[t - 1] : 0;
    for (int i = lo; i < hi; ++i){ offsets[i] = base; cursor[i] = base; base += cnt[i]; }
    if (t == 1023) offsets[N] = part[1023];
}

__global__ void k_scatter(const int* __restrict__ src, const int* __restrict__ dst,
                          const float* __restrict__ attr, const float* __restrict__ x,
                          const float* __restrict__ Wl, const float* __restrict__ Wr,
                          const float* __restrict__ We, const float* __restrict__ bsum,
                          const float* __restrict__ att,
                          int* __restrict__ cursor, float4* __restrict__ sorted, int E){
    int e = blockIdx.x * 256 + threadIdx.x;
    if (e >= E) return;
    int s = src[e], d = dst[e];
    float xs = x[s], xd = x[d], a = attr[e];
    float l0 = head_logit(xs, xd, a, Wl, Wr, We, bsum, att, 0);
    float l1 = head_logit(xs, xd, a, Wl, Wr, We, bsum, att, 1);
    int pos = atomicAdd(&cursor[d], 1);
    sorted[pos] = make_float4(xs, a, l0, l1);
}

__global__ void k_node(const float* __restrict__ x,
                       const int* __restrict__ offsets,
                       const float4* __restrict__ sorted,
                       const float* __restrict__ Wl, const float* __restrict__ Wr,
                       const float* __restrict__ We, const float* __restrict__ bsum,
                       const float* __restrict__ att,
                       float* __restrict__ sres, int N){
    int i = blockIdx.x * 256 + threadIdx.x;
    if (i >= N) return;
    int st = offsets[i], en = offsets[i + 1];
    float m0 = -3.4e38f, d0 = 0.f, n0 = 0.f;
    float m1 = -3.4e38f, d1 = 0.f, n1 = 0.f;
    float asum = 0.f;
    for (int p = st; p < en; ++p){
        float4 v = sorted[p];
        asum += v.y;
        float mn0 = fmaxf(m0, v.z);
        float s0 = expf(m0 - mn0), p0 = expf(v.z - mn0);
        d0 = fmaf(d0, s0, p0); n0 = fmaf(n0, s0, p0 * v.x); m0 = mn0;
        float mn1 = fmaxf(m1, v.w);
        float s1 = expf(m1 - mn1), p1 = expf(v.w - mn1);
        d1 = fmaf(d1, s1, p1); n1 = fmaf(n1, s1, p1 * v.x); m1 = mn1;
    }
    float xi = x[i];
    int dg = en - st;
    float la = asum / (float)max(dg, 1);
    float l0 = head_logit(xi, xi, la, Wl, Wr, We, bsum, att, 0);
    float l1 = head_logit(xi, xi, la, Wl, Wr, We, bsum, att, 1);
    {
        float mn = fmaxf(m0, l0);
        float s = expf(m0 - mn), p = expf(l0 - mn);
        d0 = fmaf(d0, s, p); n0 = fmaf(n0, s, p * xi);
    }
    {
        float mn = fmaxf(m1, l1);
        float s = expf(m1 - mn), p = expf(l1 - mn);
        d1 = fmaf(d1, s, p); n1 = fmaf(n1, s, p * xi);
    }
    sres[2 * i]     = n0 / d0;
    sres[2 * i + 1] = n1 / d1;
}

extern "C" void kernel_launch(void* const* d_in, const int* in_sizes, int n_in,
                              void* d_out, int out_size, void* d_ws, size_t ws_size,
                              hipStream_t stream) {
    const float* x    = (const float*)d_in[0];
    const int*   ei   = (const int*)  d_in[1];
    const float* attr = (const float*)d_in[2];
    const float* Wl   = (const float*)d_in[3];
    const float* bl   = (const float*)d_in[4];
    const float* Wr   = (const float*)d_in[5];
    const float* br   = (const float*)d_in[6];
    const float* We   = (const float*)d_in[7];
    const float* att  = (const float*)d_in[8];
    const float* bias = (const float*)d_in[9];
    float* out = (float*)d_out;

    const int N = in_sizes[0];       // 50000
    const int E = in_sizes[2];       // 800000
    const int* src = ei;
    const int* dst = ei + E;

    char* w = (char*)d_ws;
    size_t needF = (size_t)E * 16 + (size_t)N * MAXDEG * 4 + (size_t)N * 4
                 + (size_t)N * 8 + 1024;

    if (ws_size >= needF){
        // ---- fast path ----
        float4* payload = (float4*)w;                       // E float4
        int*    slot    = (int*)(w + (size_t)E * 16);       // N*64
        int*    deg     = slot + (size_t)N * MAXDEG;        // N
        float*  sres    = (float*)(deg + N);                // 2N
        float*  bsum    = sres + 2 * (size_t)N;             // 128
        float*  bb      = bsum + 128;                       // 128

        hipMemsetAsync(deg, 0, (size_t)N * sizeof(int), stream);
        k_prep<<<1, 128, 0, stream>>>(bl, br, bias, bsum, bb);
        k_edge<<<(E + 255) / 256, 256, 0, stream>>>(src, dst, attr, x,
                                                    Wl, Wr, We, bsum, att,
                                                    deg, slot, payload, E);
        k_node4<<<(4 * N + 255) / 256, 256, 0, stream>>>(x, deg, slot, payload,
                                                         Wl, Wr, We, bsum, att, sres, N);
        k_final4<<<((size_t)N * 32 + 255) / 256, 256, 0, stream>>>(sres, Wl, bb,
                                                                   (float4*)out, N * 32);
    } else {
        // ---- fallback: round-2 structure ----
        float4* sorted  = (float4*)w;                        // E float4
        float*  sres    = (float*)(w + (size_t)E * 16);      // 2N
        float*  bsum    = sres + 2 * (size_t)N;              // 128
        float*  bb      = bsum + 128;                        // 128
        int*    cnt     = (int*)(bb + 128);                  // N
        int*    offsets = cnt + N;                           // N+1
        int*    cursor  = offsets + N + 1;                   // N

        hipMemsetAsync(cnt, 0, (size_t)N * sizeof(int), stream);
        k_prep<<<1, 128, 0, stream>>>(bl, br, bias, bsum, bb);
        k_count<<<(E + 255) / 256, 256, 0, stream>>>(dst, cnt, E);
        k_scan<<<1, 1024, 0, stream>>>(cnt, offsets, cursor, N);
        k_scatter<<<(E + 255) / 256, 256, 0, stream>>>(src, dst, attr, x,
                                                       Wl, Wr, We, bsum, att,
                                                       cursor, sorted, E);
        k_node<<<(N + 255) / 256, 256, 0, stream>>>(x, offsets, sorted,
                                                    Wl, Wr, We, bsum, att, sres, N);
        k_final4<<<((size_t)N * 32 + 255) / 256, 256, 0, stream>>>(sres, Wl, bb,
                                                                   (float4*)out, N * 32);
    }
}

// Round 4
// 96.677 us; speedup vs baseline: 3.6447x; 1.0711x over previous
//
#include <hip/hip_runtime.h>

#define NEG 0.2f

// per-head GATv2 logit from 3 scalars; weight arrays are wave-uniform kernel
// args -> compiler emits scalar loads; bl+br folded in (both zeros in practice
// but not assumed).
__device__ __forceinline__ float head_logit(float xs, float xd, float a,
                                            const float* __restrict__ Wl,
                                            const float* __restrict__ Wr,
                                            const float* __restrict__ We,
                                            const float* __restrict__ bl,
                                            const float* __restrict__ br,
                                            const float* __restrict__ att,
                                            int h){
    float acc = 0.f;
    const int base = h * 64;
    #pragma unroll
    for (int c = 0; c < 64; ++c){
        const int hc = base + c;
        float v = fmaf(xs, Wl[hc], fmaf(xd, Wr[hc], fmaf(a, We[hc], bl[hc] + br[hc])));
        float g = fmaxf(v, NEG * v);          // leaky_relu, slope < 1
        acc = fmaf(g, att[hc], acc);
    }
    return acc;
}

// single edge pass: compute logits, link edge into its destination's chain.
// exactly ONE scattered-sector op per edge (the atomicExch); nxt/payload
// writes are coalesced in edge order.
__global__ void k_edge(const int* __restrict__ src, const int* __restrict__ dst,
                       const float* __restrict__ attr, const float* __restrict__ x,
                       const float* __restrict__ Wl, const float* __restrict__ Wr,
                       const float* __restrict__ We, const float* __restrict__ bl,
                       const float* __restrict__ br, const float* __restrict__ att,
                       int* __restrict__ head, int* __restrict__ nxt,
                       float4* __restrict__ payload, int E){
    int e = blockIdx.x * 256 + threadIdx.x;
    if (e >= E) return;
    int s = src[e], d = dst[e];
    float xs = x[s], xd = x[d], a = attr[e];
    float l0 = head_logit(xs, xd, a, Wl, Wr, We, bl, br, att, 0);
    float l1 = head_logit(xs, xd, a, Wl, Wr, We, bl, br, att, 1);
    payload[e] = make_float4(xs, a, l0, l1);          // coalesced 16B
    int prev = atomicExch(&head[d], e);               // the one scattered op
    nxt[e] = prev;                                    // coalesced 4B
}

// per node: walk the chain with exact online softmax, add self-loop
// (attr = mean of incoming, src = dst = i), then rank-1 expand the output row.
__global__ void k_node(const float* __restrict__ x,
                       const int* __restrict__ head, const int* __restrict__ nxt,
                       const float4* __restrict__ payload,
                       const float* __restrict__ Wl, const float* __restrict__ Wr,
                       const float* __restrict__ We, const float* __restrict__ bl,
                       const float* __restrict__ br, const float* __restrict__ att,
                       const float* __restrict__ bias,
                       float4* __restrict__ out, int N){
    int i = blockIdx.x * 256 + threadIdx.x;
    if (i >= N) return;
    float m0 = -3.4e38f, d0 = 0.f, n0 = 0.f;
    float m1 = -3.4e38f, d1 = 0.f, n1 = 0.f;
    float asum = 0.f;
    int deg = 0;
    for (int e = head[i]; e >= 0; e = nxt[e]){
        float4 v = payload[e];                 // (xs, a, l0, l1)
        ++deg;
        asum += v.y;
        float mn0 = fmaxf(m0, v.z);
        float s0 = expf(m0 - mn0), p0 = expf(v.z - mn0);
        d0 = fmaf(d0, s0, p0);
        n0 = fmaf(n0, s0, p0 * v.x);
        m0 = mn0;
        float mn1 = fmaxf(m1, v.w);
        float s1 = expf(m1 - mn1), p1 = expf(v.w - mn1);
        d1 = fmaf(d1, s1, p1);
        n1 = fmaf(n1, s1, p1 * v.x);
        m1 = mn1;
    }
    float xi = x[i];
    float la = asum / (float)max(deg, 1);
    float l0 = head_logit(xi, xi, la, Wl, Wr, We, bl, br, att, 0);
    float l1 = head_logit(xi, xi, la, Wl, Wr, We, bl, br, att, 1);
    {
        float mn = fmaxf(m0, l0);
        float s = expf(m0 - mn), p = expf(l0 - mn);
        d0 = fmaf(d0, s, p);
        n0 = fmaf(n0, s, p * xi);
    }
    {
        float mn = fmaxf(m1, l1);
        float s = expf(m1 - mn), p = expf(l1 - mn);
        d1 = fmaf(d1, s, p);
        n1 = fmaf(n1, s, p * xi);
    }
    float sres0 = n0 / d0;
    float sres1 = n1 / d1;

    // fused rank-1 expansion: out[i, h*64+c] = sres_h * Wl[hc] + bl[hc] + bias[hc]
    float4* orow = out + (size_t)i * 32;
    const float4* W4 = (const float4*)Wl;
    const float4* b4 = (const float4*)bl;
    const float4* z4 = (const float4*)bias;
    #pragma unroll 4
    for (int q = 0; q < 32; ++q){
        float s = (q < 16) ? sres0 : sres1;
        float4 wv = W4[q], bv = b4[q], zv = z4[q];
        orow[q] = make_float4(fmaf(s, wv.x, bv.x + zv.x),
                              fmaf(s, wv.y, bv.y + zv.y),
                              fmaf(s, wv.z, bv.z + zv.z),
                              fmaf(s, wv.w, bv.w + zv.w));
    }
}

extern "C" void kernel_launch(void* const* d_in, const int* in_sizes, int n_in,
                              void* d_out, int out_size, void* d_ws, size_t ws_size,
                              hipStream_t stream) {
    const float* x    = (const float*)d_in[0];
    const int*   ei   = (const int*)  d_in[1];
    const float* attr = (const float*)d_in[2];
    const float* Wl   = (const float*)d_in[3];
    const float* bl   = (const float*)d_in[4];
    const float* Wr   = (const float*)d_in[5];
    const float* br   = (const float*)d_in[6];
    const float* We   = (const float*)d_in[7];
    const float* att  = (const float*)d_in[8];
    const float* bias = (const float*)d_in[9];
    float* out = (float*)d_out;

    const int N = in_sizes[0];       // 50000
    const int E = in_sizes[2];       // 800000
    const int* src = ei;
    const int* dst = ei + E;

    // workspace: payload [E]float4 | nxt [E]int | head [N]int   (~16.2 MB)
    char* w = (char*)d_ws;
    float4* payload = (float4*)w;
    int*    nxt     = (int*)(w + (size_t)E * 16);
    int*    head    = nxt + E;

    // head[i] = -1 sentinel
    hipMemsetAsync(head, 0xFF, (size_t)N * sizeof(int), stream);

    k_edge<<<(E + 255) / 256, 256, 0, stream>>>(src, dst, attr, x,
                                                Wl, Wr, We, bl, br, att,
                                                head, nxt, payload, E);
    k_node<<<(N + 255) / 256, 256, 0, stream>>>(x, head, nxt, payload,
                                                Wl, Wr, We, bl, br, att, bias,
                                                (float4*)out, N);
}

// Round 5
// 89.872 us; speedup vs baseline: 3.9206x; 1.0757x over previous
//
#include <hip/hip_runtime.h>

#define NEG 0.2f

__device__ __forceinline__ float leaky(float v){ return fmaxf(v, NEG * v); }

// ---------------------------------------------------------------------------
// k_edge: 16 lanes per edge; lane (t&15) owns 8 channels, weights in VGPRs.
// Per edge: compute both head logits via 8-lane shfl reduction, then ONE
// scattered op (atomicExch into dst chain) from the group leader; payload/nxt
// writes are coalesced (adjacent groups hold adjacent e).
// ---------------------------------------------------------------------------
__global__ void __launch_bounds__(256) k_edge(
        const int* __restrict__ src, const int* __restrict__ dst,
        const float* __restrict__ attr, const float* __restrict__ x,
        const float* __restrict__ Wl, const float* __restrict__ Wr,
        const float* __restrict__ We, const float* __restrict__ bl,
        const float* __restrict__ br, const float* __restrict__ att,
        int* __restrict__ head, int* __restrict__ nxt,
        float4* __restrict__ payload, int E){
    const int sub = threadIdx.x & 15;              // channel group 0..15
    // preload this lane's 8 channels of each weight array (hc = sub*8 .. sub*8+7)
    const float4* Wl4 = (const float4*)Wl;
    const float4* Wr4 = (const float4*)Wr;
    const float4* We4 = (const float4*)We;
    const float4* bl4 = (const float4*)bl;
    const float4* br4 = (const float4*)br;
    const float4* at4 = (const float4*)att;
    const int q = sub * 2;
    float4 wl0 = Wl4[q], wl1 = Wl4[q+1];
    float4 wr0 = Wr4[q], wr1 = Wr4[q+1];
    float4 we0 = We4[q], we1 = We4[q+1];
    float4 b0  = bl4[q], b1  = bl4[q+1];
    float4 c0  = br4[q], c1  = br4[q+1];
    float4 a0  = at4[q], a1  = at4[q+1];
    b0.x += c0.x; b0.y += c0.y; b0.z += c0.z; b0.w += c0.w;
    b1.x += c1.x; b1.y += c1.y; b1.z += c1.z; b1.w += c1.w;

    const int gid     = (blockIdx.x * 256 + threadIdx.x) >> 4;
    const int ngroups = (gridDim.x * 256) >> 4;

    for (int e = gid; e < E; e += ngroups){
        int s = src[e], d = dst[e];                // broadcast within group
        float xs = x[s], xd = x[d], a = attr[e];
        float acc;
        {
            float v0 = fmaf(xs, wl0.x, fmaf(xd, wr0.x, fmaf(a, we0.x, b0.x)));
            float v1 = fmaf(xs, wl0.y, fmaf(xd, wr0.y, fmaf(a, we0.y, b0.y)));
            float v2 = fmaf(xs, wl0.z, fmaf(xd, wr0.z, fmaf(a, we0.z, b0.z)));
            float v3 = fmaf(xs, wl0.w, fmaf(xd, wr0.w, fmaf(a, we0.w, b0.w)));
            acc  = leaky(v0) * a0.x;
            acc  = fmaf(leaky(v1), a0.y, acc);
            acc  = fmaf(leaky(v2), a0.z, acc);
            acc  = fmaf(leaky(v3), a0.w, acc);
            v0 = fmaf(xs, wl1.x, fmaf(xd, wr1.x, fmaf(a, we1.x, b1.x)));
            v1 = fmaf(xs, wl1.y, fmaf(xd, wr1.y, fmaf(a, we1.y, b1.y)));
            v2 = fmaf(xs, wl1.z, fmaf(xd, wr1.z, fmaf(a, we1.z, b1.z)));
            v3 = fmaf(xs, wl1.w, fmaf(xd, wr1.w, fmaf(a, we1.w, b1.w)));
            acc  = fmaf(leaky(v0), a1.x, acc);
            acc  = fmaf(leaky(v1), a1.y, acc);
            acc  = fmaf(leaky(v2), a1.z, acc);
            acc  = fmaf(leaky(v3), a1.w, acc);
        }
        // reduce 8 lanes -> per-half sums (lanes 0-7: head0, 8-15: head1)
        acc += __shfl_xor(acc, 1);
        acc += __shfl_xor(acc, 2);
        acc += __shfl_xor(acc, 4);
        float other = __shfl_xor(acc, 8);          // leader: head1's sum
        if (sub == 0){
            payload[e] = make_float4(xs, a, acc, other);   // (xs, a, l0, l1)
            int prev = atomicExch(&head[d], e);            // one scattered op
            nxt[e] = prev;                                  // coalesced
        }
    }
}

// ---------------------------------------------------------------------------
// k_walk: thread per node; chain walk with exact online softmax; self-loop
// logit via packed LDS table (one ds_read_b128 per channel); writes sres[2N].
// ---------------------------------------------------------------------------
__global__ void __launch_bounds__(256) k_walk(
        const float* __restrict__ x,
        const int* __restrict__ head, const int* __restrict__ nxt,
        const float4* __restrict__ payload,
        const float* __restrict__ Wl, const float* __restrict__ Wr,
        const float* __restrict__ We, const float* __restrict__ bl,
        const float* __restrict__ br, const float* __restrict__ att,
        float* __restrict__ sres, int N){
    __shared__ float4 pk[128];      // (Wl+Wr, We, bl+br, att) per channel
    int t = threadIdx.x;
    if (t < 128)
        pk[t] = make_float4(Wl[t] + Wr[t], We[t], bl[t] + br[t], att[t]);
    __syncthreads();

    int i = blockIdx.x * 256 + t;
    if (i >= N) return;
    float m0 = -3.4e38f, d0 = 0.f, n0 = 0.f;
    float m1 = -3.4e38f, d1 = 0.f, n1 = 0.f;
    float asum = 0.f;
    int deg = 0;
    for (int e = head[i]; e >= 0; e = nxt[e]){
        float4 v = payload[e];                 // (xs, a, l0, l1)
        ++deg;
        asum += v.y;
        float mn0 = fmaxf(m0, v.z);
        float s0 = __expf(m0 - mn0), p0 = __expf(v.z - mn0);
        d0 = fmaf(d0, s0, p0);
        n0 = fmaf(n0, s0, p0 * v.x);
        m0 = mn0;
        float mn1 = fmaxf(m1, v.w);
        float s1 = __expf(m1 - mn1), p1 = __expf(v.w - mn1);
        d1 = fmaf(d1, s1, p1);
        n1 = fmaf(n1, s1, p1 * v.x);
        m1 = mn1;
    }
    float xi = x[i];
    float la = asum / (float)max(deg, 1);
    float l0 = 0.f, l1 = 0.f;
    #pragma unroll 8
    for (int c = 0; c < 64; ++c){
        float4 p = pk[c];
        float v = fmaf(xi, p.x, fmaf(la, p.y, p.z));
        l0 = fmaf(leaky(v), p.w, l0);
    }
    #pragma unroll 8
    for (int c = 64; c < 128; ++c){
        float4 p = pk[c];
        float v = fmaf(xi, p.x, fmaf(la, p.y, p.z));
        l1 = fmaf(leaky(v), p.w, l1);
    }
    {
        float mn = fmaxf(m0, l0);
        float s = __expf(m0 - mn), p = __expf(l0 - mn);
        d0 = fmaf(d0, s, p);
        n0 = fmaf(n0, s, p * xi);
    }
    {
        float mn = fmaxf(m1, l1);
        float s = __expf(m1 - mn), p = __expf(l1 - mn);
        d1 = fmaf(d1, s, p);
        n1 = fmaf(n1, s, p * xi);
    }
    sres[2 * i]     = n0 / d0;
    sres[2 * i + 1] = n1 / d1;
}

// rank-1 expansion: out[i, hc] = sres[i,h] * Wl[hc] + (bl+bias)[hc]
__global__ void __launch_bounds__(256) k_final4(
        const float* __restrict__ sres,
        const float* __restrict__ Wl, const float* __restrict__ bl,
        const float* __restrict__ bias,
        float4* __restrict__ out, int total4){
    int t = blockIdx.x * 256 + threadIdx.x;
    if (t >= total4) return;
    int i = t >> 5;
    int q = t & 31;                  // float4 index within 128-wide row
    int h = q >> 4;
    float s = sres[2 * i + h];
    float4 wv = ((const float4*)Wl)[q];
    float4 bv = ((const float4*)bl)[q];
    float4 zv = ((const float4*)bias)[q];
    out[t] = make_float4(fmaf(s, wv.x, bv.x + zv.x), fmaf(s, wv.y, bv.y + zv.y),
                         fmaf(s, wv.z, bv.z + zv.z), fmaf(s, wv.w, bv.w + zv.w));
}

extern "C" void kernel_launch(void* const* d_in, const int* in_sizes, int n_in,
                              void* d_out, int out_size, void* d_ws, size_t ws_size,
                              hipStream_t stream) {
    const float* x    = (const float*)d_in[0];
    const int*   ei   = (const int*)  d_in[1];
    const float* attr = (const float*)d_in[2];
    const float* Wl   = (const float*)d_in[3];
    const float* bl   = (const float*)d_in[4];
    const float* Wr   = (const float*)d_in[5];
    const float* br   = (const float*)d_in[6];
    const float* We   = (const float*)d_in[7];
    const float* att  = (const float*)d_in[8];
    const float* bias = (const float*)d_in[9];
    float* out = (float*)d_out;

    const int N = in_sizes[0];       // 50000
    const int E = in_sizes[2];       // 800000
    const int* src = ei;
    const int* dst = ei + E;

    // workspace: payload [E]float4 | nxt [E]int | head [N]int | sres [2N]float
    char* w = (char*)d_ws;
    float4* payload = (float4*)w;
    int*    nxt     = (int*)(w + (size_t)E * 16);
    int*    head    = nxt + E;
    float*  sres    = (float*)(head + N);

    hipMemsetAsync(head, 0xFF, (size_t)N * sizeof(int), stream);   // -1 sentinel

    k_edge<<<2048, 256, 0, stream>>>(src, dst, attr, x,
                                     Wl, Wr, We, bl, br, att,
                                     head, nxt, payload, E);
    k_walk<<<(N + 255) / 256, 256, 0, stream>>>(x, head, nxt, payload,
                                                Wl, Wr, We, bl, br, att,
                                                sres, N);
    k_final4<<<((size_t)N * 32 + 255) / 256, 256, 0, stream>>>(sres, Wl, bl, bias,
                                                               (float4*)out, N * 32);
}

// Round 6
// 86.221 us; speedup vs baseline: 4.0867x; 1.0423x over previous
//
#include <hip/hip_runtime.h>

#define NEG 0.2f

typedef float f4v __attribute__((ext_vector_type(4)));

__device__ __forceinline__ float leaky(float v){ return fmaxf(v, NEG * v); }

// ---------------------------------------------------------------------------
// k_edge: 16 lanes per edge; lane (t&15) owns 8 channels, weights in VGPRs.
// ONE scattered op per edge (atomicExch into one of 4 sub-chains of dst),
// issued EARLY so its return latency hides under the logit computation.
// payload/nxt writes are coalesced nontemporal stores.
// ---------------------------------------------------------------------------
__global__ void __launch_bounds__(256) k_edge(
        const int* __restrict__ src, const int* __restrict__ dst,
        const float* __restrict__ attr, const float* __restrict__ x,
        const float* __restrict__ Wl, const float* __restrict__ Wr,
        const float* __restrict__ We, const float* __restrict__ bl,
        const float* __restrict__ br, const float* __restrict__ att,
        int* __restrict__ head4, int* __restrict__ nxt,
        float4* __restrict__ payload, int E){
    const int sub = threadIdx.x & 15;              // channel group 0..15
    const float4* Wl4 = (const float4*)Wl;
    const float4* Wr4 = (const float4*)Wr;
    const float4* We4 = (const float4*)We;
    const float4* bl4 = (const float4*)bl;
    const float4* br4 = (const float4*)br;
    const float4* at4 = (const float4*)att;
    const int q = sub * 2;
    float4 wl0 = Wl4[q], wl1 = Wl4[q+1];
    float4 wr0 = Wr4[q], wr1 = Wr4[q+1];
    float4 we0 = We4[q], we1 = We4[q+1];
    float4 b0  = bl4[q], b1  = bl4[q+1];
    float4 c0  = br4[q], c1  = br4[q+1];
    float4 a0  = at4[q], a1  = at4[q+1];
    b0.x += c0.x; b0.y += c0.y; b0.z += c0.z; b0.w += c0.w;
    b1.x += c1.x; b1.y += c1.y; b1.z += c1.z; b1.w += c1.w;

    const int gid     = (blockIdx.x * 256 + threadIdx.x) >> 4;
    const int ngroups = (gridDim.x * 256) >> 4;

    for (int e = gid; e < E; e += ngroups){
        int s = src[e], d = dst[e];                // broadcast within group
        int prev = 0;
        if (sub == 0)                              // early: hide atomic latency
            prev = atomicExch(&head4[(d << 2) + (e & 3)], e);
        float xs = x[s], xd = x[d], a = attr[e];
        float acc;
        {
            float v0 = fmaf(xs, wl0.x, fmaf(xd, wr0.x, fmaf(a, we0.x, b0.x)));
            float v1 = fmaf(xs, wl0.y, fmaf(xd, wr0.y, fmaf(a, we0.y, b0.y)));
            float v2 = fmaf(xs, wl0.z, fmaf(xd, wr0.z, fmaf(a, we0.z, b0.z)));
            float v3 = fmaf(xs, wl0.w, fmaf(xd, wr0.w, fmaf(a, we0.w, b0.w)));
            acc  = leaky(v0) * a0.x;
            acc  = fmaf(leaky(v1), a0.y, acc);
            acc  = fmaf(leaky(v2), a0.z, acc);
            acc  = fmaf(leaky(v3), a0.w, acc);
            v0 = fmaf(xs, wl1.x, fmaf(xd, wr1.x, fmaf(a, we1.x, b1.x)));
            v1 = fmaf(xs, wl1.y, fmaf(xd, wr1.y, fmaf(a, we1.y, b1.y)));
            v2 = fmaf(xs, wl1.z, fmaf(xd, wr1.z, fmaf(a, we1.z, b1.z)));
            v3 = fmaf(xs, wl1.w, fmaf(xd, wr1.w, fmaf(a, we1.w, b1.w)));
            acc  = fmaf(leaky(v0), a1.x, acc);
            acc  = fmaf(leaky(v1), a1.y, acc);
            acc  = fmaf(leaky(v2), a1.z, acc);
            acc  = fmaf(leaky(v3), a1.w, acc);
        }
        // reduce: lanes 0-7 -> head0 sum, lanes 8-15 -> head1 sum
        acc += __shfl_xor(acc, 1);
        acc += __shfl_xor(acc, 2);
        acc += __shfl_xor(acc, 4);
        float other = __shfl_xor(acc, 8);          // on lane 0: head1's sum
        if (sub == 0){
            f4v pv = { xs, a, acc, other };
            __builtin_nontemporal_store(pv, (f4v*)&payload[e]);
            __builtin_nontemporal_store(prev, &nxt[e]);
        }
    }
}

// ---------------------------------------------------------------------------
// k_walk: 4 lanes per node, each walks one sub-chain with exact online
// softmax; shfl merge; 4-way-parallel self-loop logit from packed LDS table.
// ---------------------------------------------------------------------------
__global__ void __launch_bounds__(256) k_walk(
        const float* __restrict__ x,
        const int* __restrict__ head4, const int* __restrict__ nxt,
        const float4* __restrict__ payload,
        const float* __restrict__ Wl, const float* __restrict__ Wr,
        const float* __restrict__ We, const float* __restrict__ bl,
        const float* __restrict__ br, const float* __restrict__ att,
        float* __restrict__ sres, int N){
    __shared__ float4 pk[128];      // (Wl+Wr, We, bl+br, att) per channel
    int t = threadIdx.x;
    if (t < 128)
        pk[t] = make_float4(Wl[t] + Wr[t], We[t], bl[t] + br[t], att[t]);
    __syncthreads();

    int g = blockIdx.x * 256 + t;
    int i = g >> 2, sub = g & 3;
    if (i >= N) return;

    float m0 = -3.4e38f, d0 = 0.f, n0 = 0.f;
    float m1 = -3.4e38f, d1 = 0.f, n1 = 0.f;
    float asum = 0.f;
    int deg = 0;
    for (int e = head4[(i << 2) + sub]; e >= 0; e = nxt[e]){
        float4 v = payload[e];                 // (xs, a, l0, l1)
        ++deg;
        asum += v.y;
        float mn0 = fmaxf(m0, v.z);
        float s0 = __expf(m0 - mn0), p0 = __expf(v.z - mn0);
        d0 = fmaf(d0, s0, p0);
        n0 = fmaf(n0, s0, p0 * v.x);
        m0 = mn0;
        float mn1 = fmaxf(m1, v.w);
        float s1 = __expf(m1 - mn1), p1 = __expf(v.w - mn1);
        d1 = fmaf(d1, s1, p1);
        n1 = fmaf(n1, s1, p1 * v.x);
        m1 = mn1;
    }
    // merge the 4 lanes' online-softmax partials
    #pragma unroll
    for (int off = 1; off < 4; off <<= 1){
        float om0 = __shfl_xor(m0, off), od0 = __shfl_xor(d0, off), on0 = __shfl_xor(n0, off);
        float om1 = __shfl_xor(m1, off), od1 = __shfl_xor(d1, off), on1 = __shfl_xor(n1, off);
        asum += __shfl_xor(asum, off);
        deg  += __shfl_xor(deg, off);
        float mn = fmaxf(m0, om0);
        d0 = d0 * __expf(m0 - mn) + od0 * __expf(om0 - mn);
        n0 = n0 * __expf(m0 - mn) + on0 * __expf(om0 - mn);
        m0 = mn;
        mn = fmaxf(m1, om1);
        d1 = d1 * __expf(m1 - mn) + od1 * __expf(om1 - mn);
        n1 = n1 * __expf(m1 - mn) + on1 * __expf(om1 - mn);
        m1 = mn;
    }
    // self-loop logits, 32 channels per lane: lanes 0,1 -> head0; 2,3 -> head1
    float xi = x[i];
    float la = asum / (float)max(deg, 1);
    float pl = 0.f;
    #pragma unroll 8
    for (int k = 0; k < 32; ++k){
        float4 p = pk[sub * 32 + k];
        float v = fmaf(xi, p.x, fmaf(la, p.y, p.z));
        pl = fmaf(leaky(v), p.w, pl);
    }
    pl += __shfl_xor(pl, 1);                 // lane0: l0, lane2: l1
    int lane = threadIdx.x & 63;
    int base = lane & ~3;
    float l0 = __shfl(pl, base);
    float l1 = __shfl(pl, base + 2);
    if (sub == 0){
        float mn = fmaxf(m0, l0);
        float s = __expf(m0 - mn), p = __expf(l0 - mn);
        d0 = fmaf(d0, s, p);
        n0 = fmaf(n0, s, p * xi);
        mn = fmaxf(m1, l1);
        s = __expf(m1 - mn); p = __expf(l1 - mn);
        d1 = fmaf(d1, s, p);
        n1 = fmaf(n1, s, p * xi);
        sres[2 * i]     = n0 / d0;
        sres[2 * i + 1] = n1 / d1;
    }
}

// rank-1 expansion: out[i, hc] = sres[i,h] * Wl[hc] + (bl+bias)[hc]
__global__ void __launch_bounds__(256) k_final4(
        const float* __restrict__ sres,
        const float* __restrict__ Wl, const float* __restrict__ bl,
        const float* __restrict__ bias,
        float4* __restrict__ out, int total4){
    int t = blockIdx.x * 256 + threadIdx.x;
    if (t >= total4) return;
    int i = t >> 5;
    int q = t & 31;                  // float4 index within 128-wide row
    int h = q >> 4;
    float s = sres[2 * i + h];
    float4 wv = ((const float4*)Wl)[q];
    float4 bv = ((const float4*)bl)[q];
    float4 zv = ((const float4*)bias)[q];
    out[t] = make_float4(fmaf(s, wv.x, bv.x + zv.x), fmaf(s, wv.y, bv.y + zv.y),
                         fmaf(s, wv.z, bv.z + zv.z), fmaf(s, wv.w, bv.w + zv.w));
}

extern "C" void kernel_launch(void* const* d_in, const int* in_sizes, int n_in,
                              void* d_out, int out_size, void* d_ws, size_t ws_size,
                              hipStream_t stream) {
    const float* x    = (const float*)d_in[0];
    const int*   ei   = (const int*)  d_in[1];
    const float* attr = (const float*)d_in[2];
    const float* Wl   = (const float*)d_in[3];
    const float* bl   = (const float*)d_in[4];
    const float* Wr   = (const float*)d_in[5];
    const float* br   = (const float*)d_in[6];
    const float* We   = (const float*)d_in[7];
    const float* att  = (const float*)d_in[8];
    const float* bias = (const float*)d_in[9];
    float* out = (float*)d_out;

    const int N = in_sizes[0];       // 50000
    const int E = in_sizes[2];       // 800000
    const int* src = ei;
    const int* dst = ei + E;

    // workspace: payload [E]float4 | nxt [E]int | head4 [4N]int | sres [2N]float
    char* w = (char*)d_ws;
    float4* payload = (float4*)w;
    int*    nxt     = (int*)(w + (size_t)E * 16);
    int*    head4   = nxt + E;
    float*  sres    = (float*)(head4 + 4 * (size_t)N);

    hipMemsetAsync(head4, 0xFF, (size_t)4 * N * sizeof(int), stream);  // -1

    k_edge<<<2048, 256, 0, stream>>>(src, dst, attr, x,
                                     Wl, Wr, We, bl, br, att,
                                     head4, nxt, payload, E);
    k_walk<<<(4 * N + 255) / 256, 256, 0, stream>>>(x, head4, nxt, payload,
                                                    Wl, Wr, We, bl, br, att,
                                                    sres, N);
    k_final4<<<((size_t)N * 32 + 255) / 256, 256, 0, stream>>>(sres, Wl, bl, bias,
                                                               (float4*)out, N * 32);
}

// Round 7
// 79.509 us; speedup vs baseline: 4.4317x; 1.0844x over previous
//
#include <hip/hip_runtime.h>

#define NEG 0.2f

typedef float f4v __attribute__((ext_vector_type(4)));

__device__ __forceinline__ float leaky(float v){ return fmaxf(v, NEG * v); }

// physical XCD id (0..7), wave-uniform; verified on gfx950 (learn_hip m09)
__device__ __forceinline__ int xcc_id(){
    int x;
    asm volatile("s_getreg_b32 %0, hwreg(HW_REG_XCC_ID)" : "=s"(x));
    return x & 7;
}

// ---------------------------------------------------------------------------
// k_edge: 16 lanes per edge, 8 channels/lane, weights preloaded in VGPRs.
// ONE scattered op per edge: a WORKGROUP-scope atomicExch that executes in the
// local XCD's L2 (no sc1 -> no fabric round-trip). Cross-XCD atomicity is not
// needed because each XCD owns its own head planes: plane = xcc*2 + (e&1).
// payload/nxt writes are coalesced nontemporal stores.
// ---------------------------------------------------------------------------
__global__ void __launch_bounds__(256) k_edge(
        const int* __restrict__ src, const int* __restrict__ dst,
        const float* __restrict__ attr, const float* __restrict__ x,
        const float* __restrict__ Wl, const float* __restrict__ Wr,
        const float* __restrict__ We, const float* __restrict__ bl,
        const float* __restrict__ br, const float* __restrict__ att,
        int* __restrict__ head, int* __restrict__ nxt,
        float4* __restrict__ payload, int E, int N){
    const int sub = threadIdx.x & 15;              // channel group 0..15
    const float4* Wl4 = (const float4*)Wl;
    const float4* Wr4 = (const float4*)Wr;
    const float4* We4 = (const float4*)We;
    const float4* bl4 = (const float4*)bl;
    const float4* br4 = (const float4*)br;
    const float4* at4 = (const float4*)att;
    const int q = sub * 2;
    float4 wl0 = Wl4[q], wl1 = Wl4[q+1];
    float4 wr0 = Wr4[q], wr1 = Wr4[q+1];
    float4 we0 = We4[q], we1 = We4[q+1];
    float4 b0  = bl4[q], b1  = bl4[q+1];
    float4 c0  = br4[q], c1  = br4[q+1];
    float4 a0  = at4[q], a1  = at4[q+1];
    b0.x += c0.x; b0.y += c0.y; b0.z += c0.z; b0.w += c0.w;
    b1.x += c1.x; b1.y += c1.y; b1.z += c1.z; b1.w += c1.w;

    const int xcc = xcc_id();                      // uniform per block
    const int gid     = (blockIdx.x * 256 + threadIdx.x) >> 4;
    const int ngroups = (gridDim.x * 256) >> 4;

    for (int e = gid; e < E; e += ngroups){
        int s = src[e], d = dst[e];                // broadcast within group
        int prev = 0;
        if (sub == 0){                             // early: hide RMW latency
            size_t hidx = (size_t)((xcc << 1) | (e & 1)) * N + d;
            prev = __hip_atomic_exchange(&head[hidx], e,
                                         __ATOMIC_RELAXED,
                                         __HIP_MEMORY_SCOPE_WORKGROUP);
        }
        float xs = x[s], xd = x[d], a = attr[e];
        float acc;
        {
            float v0 = fmaf(xs, wl0.x, fmaf(xd, wr0.x, fmaf(a, we0.x, b0.x)));
            float v1 = fmaf(xs, wl0.y, fmaf(xd, wr0.y, fmaf(a, we0.y, b0.y)));
            float v2 = fmaf(xs, wl0.z, fmaf(xd, wr0.z, fmaf(a, we0.z, b0.z)));
            float v3 = fmaf(xs, wl0.w, fmaf(xd, wr0.w, fmaf(a, we0.w, b0.w)));
            acc  = leaky(v0) * a0.x;
            acc  = fmaf(leaky(v1), a0.y, acc);
            acc  = fmaf(leaky(v2), a0.z, acc);
            acc  = fmaf(leaky(v3), a0.w, acc);
            v0 = fmaf(xs, wl1.x, fmaf(xd, wr1.x, fmaf(a, we1.x, b1.x)));
            v1 = fmaf(xs, wl1.y, fmaf(xd, wr1.y, fmaf(a, we1.y, b1.y)));
            v2 = fmaf(xs, wl1.z, fmaf(xd, wr1.z, fmaf(a, we1.z, b1.z)));
            v3 = fmaf(xs, wl1.w, fmaf(xd, wr1.w, fmaf(a, we1.w, b1.w)));
            acc  = fmaf(leaky(v0), a1.x, acc);
            acc  = fmaf(leaky(v1), a1.y, acc);
            acc  = fmaf(leaky(v2), a1.z, acc);
            acc  = fmaf(leaky(v3), a1.w, acc);
        }
        // reduce: lanes 0-7 -> head0 sum, lanes 8-15 -> head1 sum
        acc += __shfl_xor(acc, 1);
        acc += __shfl_xor(acc, 2);
        acc += __shfl_xor(acc, 4);
        float other = __shfl_xor(acc, 8);          // on lane 0: head1's sum
        if (sub == 0){
            f4v pv = { xs, a, acc, other };
            __builtin_nontemporal_store(pv, (f4v*)&payload[e]);
            __builtin_nontemporal_store(prev, &nxt[e]);
        }
    }
}

// ---------------------------------------------------------------------------
// k_walk: 16 lanes per node; lane ln walks plane-ln's sub-chain (avg length 1)
// with exact online softmax; 4-round shfl butterfly merge; self-loop logit via
// the same 8-channels-per-lane register scheme; fused rank-1 row write (each
// lane writes 2 float4s of the 512B output row).
// ---------------------------------------------------------------------------
__global__ void __launch_bounds__(256) k_walk(
        const float* __restrict__ x,
        const int* __restrict__ head, const int* __restrict__ nxt,
        const float4* __restrict__ payload,
        const float* __restrict__ Wl, const float* __restrict__ Wr,
        const float* __restrict__ We, const float* __restrict__ bl,
        const float* __restrict__ br, const float* __restrict__ att,
        const float* __restrict__ bias,
        float4* __restrict__ out, int N){
    int t = blockIdx.x * 256 + threadIdx.x;
    int i = t >> 4, ln = t & 15;
    if (i >= N) return;

    // this lane's 8 self-loop channels: hc = ln*8 .. ln*8+7 (xs == xd == xi)
    const float4* Wl4 = (const float4*)Wl;
    const float4* Wr4 = (const float4*)Wr;
    const float4* We4 = (const float4*)We;
    const float4* bl4 = (const float4*)bl;
    const float4* br4 = (const float4*)br;
    const float4* at4 = (const float4*)att;
    const int q = ln * 2;
    float4 wl0 = Wl4[q], wl1 = Wl4[q+1];
    float4 wr0 = Wr4[q], wr1 = Wr4[q+1];
    float4 we0 = We4[q], we1 = We4[q+1];
    float4 b0  = bl4[q], b1  = bl4[q+1];
    float4 c0  = br4[q], c1  = br4[q+1];
    float4 a0  = at4[q], a1  = at4[q+1];
    // combine: v = xi*(wl+wr) + la*we + (bl+br)
    wl0.x += wr0.x; wl0.y += wr0.y; wl0.z += wr0.z; wl0.w += wr0.w;
    wl1.x += wr1.x; wl1.y += wr1.y; wl1.z += wr1.z; wl1.w += wr1.w;
    b0.x += c0.x; b0.y += c0.y; b0.z += c0.z; b0.w += c0.w;
    b1.x += c1.x; b1.y += c1.y; b1.z += c1.z; b1.w += c1.w;

    // walk this lane's sub-chain
    float m0 = -3.4e38f, d0 = 0.f, n0 = 0.f;
    float m1 = -3.4e38f, d1 = 0.f, n1 = 0.f;
    float asum = 0.f;
    int deg = 0;
    for (int e = head[(size_t)ln * N + i]; e >= 0; e = nxt[e]){
        float4 v = payload[e];                 // (xs, a, l0, l1)
        ++deg;
        asum += v.y;
        float mn0 = fmaxf(m0, v.z);
        float s0 = __expf(m0 - mn0), p0 = __expf(v.z - mn0);
        d0 = fmaf(d0, s0, p0);
        n0 = fmaf(n0, s0, p0 * v.x);
        m0 = mn0;
        float mn1 = fmaxf(m1, v.w);
        float s1 = __expf(m1 - mn1), p1 = __expf(v.w - mn1);
        d1 = fmaf(d1, s1, p1);
        n1 = fmaf(n1, s1, p1 * v.x);
        m1 = mn1;
    }
    // butterfly merge across the 16 lanes of this node
    #pragma unroll
    for (int off = 1; off < 16; off <<= 1){
        float om0 = __shfl_xor(m0, off), od0 = __shfl_xor(d0, off), on0 = __shfl_xor(n0, off);
        float om1 = __shfl_xor(m1, off), od1 = __shfl_xor(d1, off), on1 = __shfl_xor(n1, off);
        asum += __shfl_xor(asum, off);
        deg  += __shfl_xor(deg, off);
        float mn = fmaxf(m0, om0);
        d0 = d0 * __expf(m0 - mn) + od0 * __expf(om0 - mn);
        n0 = n0 * __expf(m0 - mn) + on0 * __expf(om0 - mn);
        m0 = mn;
        mn = fmaxf(m1, om1);
        d1 = d1 * __expf(m1 - mn) + od1 * __expf(om1 - mn);
        n1 = n1 * __expf(m1 - mn) + on1 * __expf(om1 - mn);
        m1 = mn;
    }
    // self-loop logit, 8 channels per lane
    float xi = x[i];
    float la = asum / (float)max(deg, 1);
    float pl;
    {
        float v0 = fmaf(xi, wl0.x, fmaf(la, we0.x, b0.x));
        float v1 = fmaf(xi, wl0.y, fmaf(la, we0.y, b0.y));
        float v2 = fmaf(xi, wl0.z, fmaf(la, we0.z, b0.z));
        float v3 = fmaf(xi, wl0.w, fmaf(la, we0.w, b0.w));
        pl  = leaky(v0) * a0.x;
        pl  = fmaf(leaky(v1), a0.y, pl);
        pl  = fmaf(leaky(v2), a0.z, pl);
        pl  = fmaf(leaky(v3), a0.w, pl);
        v0 = fmaf(xi, wl1.x, fmaf(la, we1.x, b1.x));
        v1 = fmaf(xi, wl1.y, fmaf(la, we1.y, b1.y));
        v2 = fmaf(xi, wl1.z, fmaf(la, we1.z, b1.z));
        v3 = fmaf(xi, wl1.w, fmaf(la, we1.w, b1.w));
        pl  = fmaf(leaky(v0), a1.x, pl);
        pl  = fmaf(leaky(v1), a1.y, pl);
        pl  = fmaf(leaky(v2), a1.z, pl);
        pl  = fmaf(leaky(v3), a1.w, pl);
    }
    pl += __shfl_xor(pl, 1);
    pl += __shfl_xor(pl, 2);
    pl += __shfl_xor(pl, 4);                 // lanes 0-7: l0, lanes 8-15: l1
    float other = __shfl_xor(pl, 8);
    float l0 = (ln < 8) ? pl : other;
    float l1 = (ln < 8) ? other : pl;
    // fold self-loop into the merged softmax state (all lanes redundantly)
    {
        float mn = fmaxf(m0, l0);
        float s = __expf(m0 - mn), p = __expf(l0 - mn);
        d0 = fmaf(d0, s, p);
        n0 = fmaf(n0, s, p * xi);
    }
    {
        float mn = fmaxf(m1, l1);
        float s = __expf(m1 - mn), p = __expf(l1 - mn);
        d1 = fmaf(d1, s, p);
        n1 = fmaf(n1, s, p * xi);
    }
    float sres0 = n0 / d0;
    float sres1 = n1 / d1;

    // fused rank-1 row write: lane ln writes float4 slots ln and ln+16
    const float* bs = bias;
    float4 w0 = Wl4[ln],      w1 = Wl4[ln + 16];
    float4 g0 = bl4[ln],      g1 = bl4[ln + 16];
    float4 z0 = ((const float4*)bs)[ln], z1 = ((const float4*)bs)[ln + 16];
    float4* orow = out + (size_t)i * 32;
    orow[ln]      = make_float4(fmaf(sres0, w0.x, g0.x + z0.x),
                                fmaf(sres0, w0.y, g0.y + z0.y),
                                fmaf(sres0, w0.z, g0.z + z0.z),
                                fmaf(sres0, w0.w, g0.w + z0.w));
    orow[ln + 16] = make_float4(fmaf(sres1, w1.x, g1.x + z1.x),
                                fmaf(sres1, w1.y, g1.y + z1.y),
                                fmaf(sres1, w1.z, g1.z + z1.z),
                                fmaf(sres1, w1.w, g1.w + z1.w));
}

extern "C" void kernel_launch(void* const* d_in, const int* in_sizes, int n_in,
                              void* d_out, int out_size, void* d_ws, size_t ws_size,
                              hipStream_t stream) {
    const float* x    = (const float*)d_in[0];
    const int*   ei   = (const int*)  d_in[1];
    const float* attr = (const float*)d_in[2];
    const float* Wl   = (const float*)d_in[3];
    const float* bl   = (const float*)d_in[4];
    const float* Wr   = (const float*)d_in[5];
    const float* br   = (const float*)d_in[6];
    const float* We   = (const float*)d_in[7];
    const float* att  = (const float*)d_in[8];
    const float* bias = (const float*)d_in[9];
    float* out = (float*)d_out;

    const int N = in_sizes[0];       // 50000
    const int E = in_sizes[2];       // 800000
    const int* src = ei;
    const int* dst = ei + E;

    // workspace: payload [E]float4 | nxt [E]int | head [16][N]int  (~19.2 MB)
    char* w = (char*)d_ws;
    float4* payload = (float4*)w;
    int*    nxt     = (int*)(w + (size_t)E * 16);
    int*    head    = nxt + E;

    hipMemsetAsync(head, 0xFF, (size_t)16 * N * sizeof(int), stream);  // -1

    k_edge<<<2048, 256, 0, stream>>>(src, dst, attr, x,
                                     Wl, Wr, We, bl, br, att,
                                     head, nxt, payload, E, N);
    k_walk<<<(16 * N + 255) / 256, 256, 0, stream>>>(x, head, nxt, payload,
                                                     Wl, Wr, We, bl, br, att, bias,
                                                     (float4*)out, N);
}

// Round 8
// 79.427 us; speedup vs baseline: 4.4362x; 1.0010x over previous
//
#include <hip/hip_runtime.h>

#define NEG 0.2f

typedef float f4v __attribute__((ext_vector_type(4)));

__device__ __forceinline__ float leaky(float v){ return fmaxf(v, NEG * v); }

// ---------------------------------------------------------------------------
// k_edge: 16-lane groups, 16 edges per group (one chunk). Lane ln owns
// channels ln*8..ln*8+7 with weights in VGPRs, and owns edge base+ln for all
// memory traffic: coalesced src/dst/attr/x loads, 16 atomicExch in flight,
// coalesced payload/nxt stores. Inner loop broadcasts edge j's scalars via
// sub-group shfl and computes both head logits; lane j keeps the result.
// ---------------------------------------------------------------------------
__global__ void __launch_bounds__(256, 6) k_edge(
        const int* __restrict__ src, const int* __restrict__ dst,
        const float* __restrict__ attr, const float* __restrict__ x,
        const float* __restrict__ Wl, const float* __restrict__ Wr,
        const float* __restrict__ We, const float* __restrict__ bl,
        const float* __restrict__ br, const float* __restrict__ att,
        int* __restrict__ head, int* __restrict__ nxt,
        float4* __restrict__ payload, int E){
    const int ln = threadIdx.x & 15;               // channel group 0..15
    const float4* Wl4 = (const float4*)Wl;
    const float4* Wr4 = (const float4*)Wr;
    const float4* We4 = (const float4*)We;
    const float4* bl4 = (const float4*)bl;
    const float4* br4 = (const float4*)br;
    const float4* at4 = (const float4*)att;
    const int q = ln * 2;
    float4 wl0 = Wl4[q], wl1 = Wl4[q+1];
    float4 wr0 = Wr4[q], wr1 = Wr4[q+1];
    float4 we0 = We4[q], we1 = We4[q+1];
    float4 b0  = bl4[q], b1  = bl4[q+1];
    float4 c0  = br4[q], c1  = br4[q+1];
    float4 a0  = at4[q], a1  = at4[q+1];
    b0.x += c0.x; b0.y += c0.y; b0.z += c0.z; b0.w += c0.w;
    b1.x += c1.x; b1.y += c1.y; b1.z += c1.z; b1.w += c1.w;

    const int gid  = (blockIdx.x * 256 + threadIdx.x) >> 4;
    const int base = gid * 16;
    if (base >= E) return;

    const int eL = base + ln;
    const bool val = eL < E;
    int   sL = 0, dL = 0;
    float aL = 0.f;
    if (val){ sL = src[eL]; dL = dst[eL]; aL = attr[eL]; }   // coalesced
    float xsL = val ? x[sL] : 0.f;                           // 16 gathers in flight
    float xdL = val ? x[dL] : 0.f;
    int prevL = 0;
    if (val)                                                  // 16 atomics in flight
        prevL = atomicExch(&head[dL * 16 + ln], eL);

    const int cnt = min(16, E - base);
    float l0L = 0.f, l1L = 0.f;
    for (int j = 0; j < cnt; ++j){
        float xs = __shfl(xsL, j, 16);
        float xd = __shfl(xdL, j, 16);
        float a  = __shfl(aL,  j, 16);
        float acc;
        {
            float v0 = fmaf(xs, wl0.x, fmaf(xd, wr0.x, fmaf(a, we0.x, b0.x)));
            float v1 = fmaf(xs, wl0.y, fmaf(xd, wr0.y, fmaf(a, we0.y, b0.y)));
            float v2 = fmaf(xs, wl0.z, fmaf(xd, wr0.z, fmaf(a, we0.z, b0.z)));
            float v3 = fmaf(xs, wl0.w, fmaf(xd, wr0.w, fmaf(a, we0.w, b0.w)));
            acc  = leaky(v0) * a0.x;
            acc  = fmaf(leaky(v1), a0.y, acc);
            acc  = fmaf(leaky(v2), a0.z, acc);
            acc  = fmaf(leaky(v3), a0.w, acc);
            v0 = fmaf(xs, wl1.x, fmaf(xd, wr1.x, fmaf(a, we1.x, b1.x)));
            v1 = fmaf(xs, wl1.y, fmaf(xd, wr1.y, fmaf(a, we1.y, b1.y)));
            v2 = fmaf(xs, wl1.z, fmaf(xd, wr1.z, fmaf(a, we1.z, b1.z)));
            v3 = fmaf(xs, wl1.w, fmaf(xd, wr1.w, fmaf(a, we1.w, b1.w)));
            acc  = fmaf(leaky(v0), a1.x, acc);
            acc  = fmaf(leaky(v1), a1.y, acc);
            acc  = fmaf(leaky(v2), a1.z, acc);
            acc  = fmaf(leaky(v3), a1.w, acc);
        }
        // lanes 0-7 -> head0 sum, lanes 8-15 -> head1 sum; then swap halves
        acc += __shfl_xor(acc, 1);
        acc += __shfl_xor(acc, 2);
        acc += __shfl_xor(acc, 4);
        float other = __shfl_xor(acc, 8);
        if (ln == j){
            l0L = (j < 8) ? acc : other;
            l1L = (j < 8) ? other : acc;
        }
    }
    if (val){
        f4v pv = { xsL, aL, l0L, l1L };
        __builtin_nontemporal_store(pv, (f4v*)&payload[eL]);   // coalesced 16B
        __builtin_nontemporal_store(prevL, &nxt[eL]);          // coalesced 4B
    }
}

// ---------------------------------------------------------------------------
// k_walk: 16 lanes per node; lane ln walks sub-chain ln (avg length 1) with
// exact online softmax; butterfly merge; self-loop logit with register
// weights; fused rank-1 row write. head is node-major [N][16] -> coalesced.
// ---------------------------------------------------------------------------
__global__ void __launch_bounds__(256, 6) k_walk(
        const float* __restrict__ x,
        const int* __restrict__ head, const int* __restrict__ nxt,
        const float4* __restrict__ payload,
        const float* __restrict__ Wl, const float* __restrict__ Wr,
        const float* __restrict__ We, const float* __restrict__ bl,
        const float* __restrict__ br, const float* __restrict__ att,
        const float* __restrict__ bias,
        float4* __restrict__ out, int N){
    int t = blockIdx.x * 256 + threadIdx.x;
    int i = t >> 4, ln = t & 15;
    if (i >= N) return;

    const float4* Wl4 = (const float4*)Wl;
    const float4* Wr4 = (const float4*)Wr;
    const float4* We4 = (const float4*)We;
    const float4* bl4 = (const float4*)bl;
    const float4* br4 = (const float4*)br;
    const float4* at4 = (const float4*)att;
    const int q = ln * 2;
    float4 wl0 = Wl4[q], wl1 = Wl4[q+1];
    float4 wr0 = Wr4[q], wr1 = Wr4[q+1];
    float4 we0 = We4[q], we1 = We4[q+1];
    float4 b0  = bl4[q], b1  = bl4[q+1];
    float4 c0  = br4[q], c1  = br4[q+1];
    float4 a0  = at4[q], a1  = at4[q+1];
    wl0.x += wr0.x; wl0.y += wr0.y; wl0.z += wr0.z; wl0.w += wr0.w;
    wl1.x += wr1.x; wl1.y += wr1.y; wl1.z += wr1.z; wl1.w += wr1.w;
    b0.x += c0.x; b0.y += c0.y; b0.z += c0.z; b0.w += c0.w;
    b1.x += c1.x; b1.y += c1.y; b1.z += c1.z; b1.w += c1.w;

    // walk this lane's sub-chain
    float m0 = -3.4e38f, d0 = 0.f, n0 = 0.f;
    float m1 = -3.4e38f, d1 = 0.f, n1 = 0.f;
    float asum = 0.f;
    int deg = 0;
    for (int e = head[(size_t)i * 16 + ln]; e >= 0; e = nxt[e]){
        float4 v = payload[e];                 // (xs, a, l0, l1)
        ++deg;
        asum += v.y;
        float mn0 = fmaxf(m0, v.z);
        float s0 = __expf(m0 - mn0), p0 = __expf(v.z - mn0);
        d0 = fmaf(d0, s0, p0);
        n0 = fmaf(n0, s0, p0 * v.x);
        m0 = mn0;
        float mn1 = fmaxf(m1, v.w);
        float s1 = __expf(m1 - mn1), p1 = __expf(v.w - mn1);
        d1 = fmaf(d1, s1, p1);
        n1 = fmaf(n1, s1, p1 * v.x);
        m1 = mn1;
    }
    // butterfly merge across the 16 lanes of this node
    #pragma unroll
    for (int off = 1; off < 16; off <<= 1){
        float om0 = __shfl_xor(m0, off), od0 = __shfl_xor(d0, off), on0 = __shfl_xor(n0, off);
        float om1 = __shfl_xor(m1, off), od1 = __shfl_xor(d1, off), on1 = __shfl_xor(n1, off);
        asum += __shfl_xor(asum, off);
        deg  += __shfl_xor(deg, off);
        float mn = fmaxf(m0, om0);
        d0 = d0 * __expf(m0 - mn) + od0 * __expf(om0 - mn);
        n0 = n0 * __expf(m0 - mn) + on0 * __expf(om0 - mn);
        m0 = mn;
        mn = fmaxf(m1, om1);
        d1 = d1 * __expf(m1 - mn) + od1 * __expf(om1 - mn);
        n1 = n1 * __expf(m1 - mn) + on1 * __expf(om1 - mn);
        m1 = mn;
    }
    // self-loop logit, 8 channels per lane
    float xi = x[i];
    float la = asum / (float)max(deg, 1);
    float pl;
    {
        float v0 = fmaf(xi, wl0.x, fmaf(la, we0.x, b0.x));
        float v1 = fmaf(xi, wl0.y, fmaf(la, we0.y, b0.y));
        float v2 = fmaf(xi, wl0.z, fmaf(la, we0.z, b0.z));
        float v3 = fmaf(xi, wl0.w, fmaf(la, we0.w, b0.w));
        pl  = leaky(v0) * a0.x;
        pl  = fmaf(leaky(v1), a0.y, pl);
        pl  = fmaf(leaky(v2), a0.z, pl);
        pl  = fmaf(leaky(v3), a0.w, pl);
        v0 = fmaf(xi, wl1.x, fmaf(la, we1.x, b1.x));
        v1 = fmaf(xi, wl1.y, fmaf(la, we1.y, b1.y));
        v2 = fmaf(xi, wl1.z, fmaf(la, we1.z, b1.z));
        v3 = fmaf(xi, wl1.w, fmaf(la, we1.w, b1.w));
        pl  = fmaf(leaky(v0), a1.x, pl);
        pl  = fmaf(leaky(v1), a1.y, pl);
        pl  = fmaf(leaky(v2), a1.z, pl);
        pl  = fmaf(leaky(v3), a1.w, pl);
    }
    pl += __shfl_xor(pl, 1);
    pl += __shfl_xor(pl, 2);
    pl += __shfl_xor(pl, 4);                 // lanes 0-7: l0, lanes 8-15: l1
    float other = __shfl_xor(pl, 8);
    float l0 = (ln < 8) ? pl : other;
    float l1 = (ln < 8) ? other : pl;
    // fold self-loop into merged softmax state (all lanes redundantly)
    {
        float mn = fmaxf(m0, l0);
        float s = __expf(m0 - mn), p = __expf(l0 - mn);
        d0 = fmaf(d0, s, p);
        n0 = fmaf(n0, s, p * xi);
    }
    {
        float mn = fmaxf(m1, l1);
        float s = __expf(m1 - mn), p = __expf(l1 - mn);
        d1 = fmaf(d1, s, p);
        n1 = fmaf(n1, s, p * xi);
    }
    float sres0 = n0 / d0;
    float sres1 = n1 / d1;

    // fused rank-1 row write: lane ln writes float4 slots ln and ln+16
    float4 w0 = Wl4[ln],      w1 = Wl4[ln + 16];
    float4 g0 = bl4[ln],      g1 = bl4[ln + 16];
    float4 z0 = ((const float4*)bias)[ln], z1 = ((const float4*)bias)[ln + 16];
    float4* orow = out + (size_t)i * 32;
    orow[ln]      = make_float4(fmaf(sres0, w0.x, g0.x + z0.x),
                                fmaf(sres0, w0.y, g0.y + z0.y),
                                fmaf(sres0, w0.z, g0.z + z0.z),
                                fmaf(sres0, w0.w, g0.w + z0.w));
    orow[ln + 16] = make_float4(fmaf(sres1, w1.x, g1.x + z1.x),
                                fmaf(sres1, w1.y, g1.y + z1.y),
                                fmaf(sres1, w1.z, g1.z + z1.z),
                                fmaf(sres1, w1.w, g1.w + z1.w));
}

extern "C" void kernel_launch(void* const* d_in, const int* in_sizes, int n_in,
                              void* d_out, int out_size, void* d_ws, size_t ws_size,
                              hipStream_t stream) {
    const float* x    = (const float*)d_in[0];
    const int*   ei   = (const int*)  d_in[1];
    const float* attr = (const float*)d_in[2];
    const float* Wl   = (const float*)d_in[3];
    const float* bl   = (const float*)d_in[4];
    const float* Wr   = (const float*)d_in[5];
    const float* br   = (const float*)d_in[6];
    const float* We   = (const float*)d_in[7];
    const float* att  = (const float*)d_in[8];
    const float* bias = (const float*)d_in[9];
    float* out = (float*)d_out;

    const int N = in_sizes[0];       // 50000
    const int E = in_sizes[2];       // 800000
    const int* src = ei;
    const int* dst = ei + E;

    // workspace: payload [E]float4 | nxt [E]int | head [N][16]int  (~19.2 MB)
    char* w = (char*)d_ws;
    float4* payload = (float4*)w;
    int*    nxt     = (int*)(w + (size_t)E * 16);
    int*    head    = nxt + E;

    hipMemsetAsync(head, 0xFF, (size_t)16 * N * sizeof(int), stream);  // -1

    int egroups = (E + 15) / 16;                    // one 16-edge chunk per group
    int eblocks = (egroups + 15) / 16;              // 16 groups per 256-thr block
    k_edge<<<eblocks, 256, 0, stream>>>(src, dst, attr, x,
                                        Wl, Wr, We, bl, br, att,
                                        head, nxt, payload, E);
    k_walk<<<((size_t)16 * N + 255) / 256, 256, 0, stream>>>(x, head, nxt, payload,
                                                             Wl, Wr, We, bl, br, att, bias,
                                                             (float4*)out, N);
}

// Round 9
// 79.354 us; speedup vs baseline: 4.4403x; 1.0009x over previous
//
#include <hip/hip_runtime.h>

#define NEG 0.2f

typedef float f4v __attribute__((ext_vector_type(4)));

__device__ __forceinline__ float leaky(float v){ return fmaxf(v, NEG * v); }

// fast -1 fill for head[] (the rocclr fillBuffer path runs at only ~67 GB/s)
__global__ void __launch_bounds__(256) k_fill(int4* __restrict__ p, int n4){
    int t = blockIdx.x * 256 + threadIdx.x;
    if (t < n4) p[t] = make_int4(-1, -1, -1, -1);
}

// ---------------------------------------------------------------------------
// k_edge: 16-lane groups, 16 edges per group (one chunk). Lane ln owns
// channels ln*8..ln*8+7 with weights in VGPRs, and owns edge base+ln for all
// memory traffic: coalesced src/dst/attr/x loads, 16 atomicExch in flight,
// coalesced payload/nxt stores. Inner loop broadcasts edge j's scalars via
// sub-group shfl and computes both head logits; lane j keeps the result.
// ---------------------------------------------------------------------------
__global__ void __launch_bounds__(256, 6) k_edge(
        const int* __restrict__ src, const int* __restrict__ dst,
        const float* __restrict__ attr, const float* __restrict__ x,
        const float* __restrict__ Wl, const float* __restrict__ Wr,
        const float* __restrict__ We, const float* __restrict__ bl,
        const float* __restrict__ br, const float* __restrict__ att,
        int* __restrict__ head, int* __restrict__ nxt,
        float4* __restrict__ payload, int E){
    const int ln = threadIdx.x & 15;               // channel group 0..15
    const float4* Wl4 = (const float4*)Wl;
    const float4* Wr4 = (const float4*)Wr;
    const float4* We4 = (const float4*)We;
    const float4* bl4 = (const float4*)bl;
    const float4* br4 = (const float4*)br;
    const float4* at4 = (const float4*)att;
    const int q = ln * 2;
    float4 wl0 = Wl4[q], wl1 = Wl4[q+1];
    float4 wr0 = Wr4[q], wr1 = Wr4[q+1];
    float4 we0 = We4[q], we1 = We4[q+1];
    float4 b0  = bl4[q], b1  = bl4[q+1];
    float4 c0  = br4[q], c1  = br4[q+1];
    float4 a0  = at4[q], a1  = at4[q+1];
    b0.x += c0.x; b0.y += c0.y; b0.z += c0.z; b0.w += c0.w;
    b1.x += c1.x; b1.y += c1.y; b1.z += c1.z; b1.w += c1.w;

    const int gid  = (blockIdx.x * 256 + threadIdx.x) >> 4;
    const int base = gid * 16;
    if (base >= E) return;

    const int eL = base + ln;
    const bool val = eL < E;
    int   sL = 0, dL = 0;
    float aL = 0.f;
    if (val){ sL = src[eL]; dL = dst[eL]; aL = attr[eL]; }   // coalesced
    float xsL = val ? x[sL] : 0.f;                           // 16 gathers in flight
    float xdL = val ? x[dL] : 0.f;
    int prevL = 0;
    if (val)                                                  // 16 atomics in flight
        prevL = atomicExch(&head[dL * 16 + ln], eL);

    const int cnt = min(16, E - base);
    float l0L = 0.f, l1L = 0.f;
    for (int j = 0; j < cnt; ++j){
        float xs = __shfl(xsL, j, 16);
        float xd = __shfl(xdL, j, 16);
        float a  = __shfl(aL,  j, 16);
        float acc;
        {
            float v0 = fmaf(xs, wl0.x, fmaf(xd, wr0.x, fmaf(a, we0.x, b0.x)));
            float v1 = fmaf(xs, wl0.y, fmaf(xd, wr0.y, fmaf(a, we0.y, b0.y)));
            float v2 = fmaf(xs, wl0.z, fmaf(xd, wr0.z, fmaf(a, we0.z, b0.z)));
            float v3 = fmaf(xs, wl0.w, fmaf(xd, wr0.w, fmaf(a, we0.w, b0.w)));
            acc  = leaky(v0) * a0.x;
            acc  = fmaf(leaky(v1), a0.y, acc);
            acc  = fmaf(leaky(v2), a0.z, acc);
            acc  = fmaf(leaky(v3), a0.w, acc);
            v0 = fmaf(xs, wl1.x, fmaf(xd, wr1.x, fmaf(a, we1.x, b1.x)));
            v1 = fmaf(xs, wl1.y, fmaf(xd, wr1.y, fmaf(a, we1.y, b1.y)));
            v2 = fmaf(xs, wl1.z, fmaf(xd, wr1.z, fmaf(a, we1.z, b1.z)));
            v3 = fmaf(xs, wl1.w, fmaf(xd, wr1.w, fmaf(a, we1.w, b1.w)));
            acc  = fmaf(leaky(v0), a1.x, acc);
            acc  = fmaf(leaky(v1), a1.y, acc);
            acc  = fmaf(leaky(v2), a1.z, acc);
            acc  = fmaf(leaky(v3), a1.w, acc);
        }
        // lanes 0-7 -> head0 sum, lanes 8-15 -> head1 sum; then swap halves
        acc += __shfl_xor(acc, 1);
        acc += __shfl_xor(acc, 2);
        acc += __shfl_xor(acc, 4);
        float other = __shfl_xor(acc, 8);
        if (ln == j){
            l0L = (j < 8) ? acc : other;
            l1L = (j < 8) ? other : acc;
        }
    }
    if (val){
        f4v pv = { xsL, aL, l0L, l1L };
        __builtin_nontemporal_store(pv, (f4v*)&payload[eL]);   // coalesced 16B
        __builtin_nontemporal_store(prevL, &nxt[eL]);          // coalesced 4B
    }
}

// ---------------------------------------------------------------------------
// k_walk: 16 lanes per node; lane ln walks sub-chain ln (avg length 1) with
// exact online softmax; butterfly merge; self-loop logit with register
// weights; fused rank-1 row write. head is node-major [N][16] -> coalesced.
// ---------------------------------------------------------------------------
__global__ void __launch_bounds__(256, 6) k_walk(
        const float* __restrict__ x,
        const int* __restrict__ head, const int* __restrict__ nxt,
        const float4* __restrict__ payload,
        const float* __restrict__ Wl, const float* __restrict__ Wr,
        const float* __restrict__ We, const float* __restrict__ bl,
        const float* __restrict__ br, const float* __restrict__ att,
        const float* __restrict__ bias,
        float4* __restrict__ out, int N){
    int t = blockIdx.x * 256 + threadIdx.x;
    int i = t >> 4, ln = t & 15;
    if (i >= N) return;

    const float4* Wl4 = (const float4*)Wl;
    const float4* Wr4 = (const float4*)Wr;
    const float4* We4 = (const float4*)We;
    const float4* bl4 = (const float4*)bl;
    const float4* br4 = (const float4*)br;
    const float4* at4 = (const float4*)att;
    const int q = ln * 2;
    float4 wl0 = Wl4[q], wl1 = Wl4[q+1];
    float4 wr0 = Wr4[q], wr1 = Wr4[q+1];
    float4 we0 = We4[q], we1 = We4[q+1];
    float4 b0  = bl4[q], b1  = bl4[q+1];
    float4 c0  = br4[q], c1  = br4[q+1];
    float4 a0  = at4[q], a1  = at4[q+1];
    wl0.x += wr0.x; wl0.y += wr0.y; wl0.z += wr0.z; wl0.w += wr0.w;
    wl1.x += wr1.x; wl1.y += wr1.y; wl1.z += wr1.z; wl1.w += wr1.w;
    b0.x += c0.x; b0.y += c0.y; b0.z += c0.z; b0.w += c0.w;
    b1.x += c1.x; b1.y += c1.y; b1.z += c1.z; b1.w += c1.w;

    // walk this lane's sub-chain
    float m0 = -3.4e38f, d0 = 0.f, n0 = 0.f;
    float m1 = -3.4e38f, d1 = 0.f, n1 = 0.f;
    float asum = 0.f;
    int deg = 0;
    for (int e = head[(size_t)i * 16 + ln]; e >= 0; e = nxt[e]){
        float4 v = payload[e];                 // (xs, a, l0, l1)
        ++deg;
        asum += v.y;
        float mn0 = fmaxf(m0, v.z);
        float s0 = __expf(m0 - mn0), p0 = __expf(v.z - mn0);
        d0 = fmaf(d0, s0, p0);
        n0 = fmaf(n0, s0, p0 * v.x);
        m0 = mn0;
        float mn1 = fmaxf(m1, v.w);
        float s1 = __expf(m1 - mn1), p1 = __expf(v.w - mn1);
        d1 = fmaf(d1, s1, p1);
        n1 = fmaf(n1, s1, p1 * v.x);
        m1 = mn1;
    }
    // butterfly merge across the 16 lanes of this node
    #pragma unroll
    for (int off = 1; off < 16; off <<= 1){
        float om0 = __shfl_xor(m0, off), od0 = __shfl_xor(d0, off), on0 = __shfl_xor(n0, off);
        float om1 = __shfl_xor(m1, off), od1 = __shfl_xor(d1, off), on1 = __shfl_xor(n1, off);
        asum += __shfl_xor(asum, off);
        deg  += __shfl_xor(deg, off);
        float mn = fmaxf(m0, om0);
        d0 = d0 * __expf(m0 - mn) + od0 * __expf(om0 - mn);
        n0 = n0 * __expf(m0 - mn) + on0 * __expf(om0 - mn);
        m0 = mn;
        mn = fmaxf(m1, om1);
        d1 = d1 * __expf(m1 - mn) + od1 * __expf(om1 - mn);
        n1 = n1 * __expf(m1 - mn) + on1 * __expf(om1 - mn);
        m1 = mn;
    }
    // self-loop logit, 8 channels per lane
    float xi = x[i];
    float la = asum / (float)max(deg, 1);
    float pl;
    {
        float v0 = fmaf(xi, wl0.x, fmaf(la, we0.x, b0.x));
        float v1 = fmaf(xi, wl0.y, fmaf(la, we0.y, b0.y));
        float v2 = fmaf(xi, wl0.z, fmaf(la, we0.z, b0.z));
        float v3 = fmaf(xi, wl0.w, fmaf(la, we0.w, b0.w));
        pl  = leaky(v0) * a0.x;
        pl  = fmaf(leaky(v1), a0.y, pl);
        pl  = fmaf(leaky(v2), a0.z, pl);
        pl  = fmaf(leaky(v3), a0.w, pl);
        v0 = fmaf(xi, wl1.x, fmaf(la, we1.x, b1.x));
        v1 = fmaf(xi, wl1.y, fmaf(la, we1.y, b1.y));
        v2 = fmaf(xi, wl1.z, fmaf(la, we1.z, b1.z));
        v3 = fmaf(xi, wl1.w, fmaf(la, we1.w, b1.w));
        pl  = fmaf(leaky(v0), a1.x, pl);
        pl  = fmaf(leaky(v1), a1.y, pl);
        pl  = fmaf(leaky(v2), a1.z, pl);
        pl  = fmaf(leaky(v3), a1.w, pl);
    }
    pl += __shfl_xor(pl, 1);
    pl += __shfl_xor(pl, 2);
    pl += __shfl_xor(pl, 4);                 // lanes 0-7: l0, lanes 8-15: l1
    float other = __shfl_xor(pl, 8);
    float l0 = (ln < 8) ? pl : other;
    float l1 = (ln < 8) ? other : pl;
    // fold self-loop into merged softmax state (all lanes redundantly)
    {
        float mn = fmaxf(m0, l0);
        float s = __expf(m0 - mn), p = __expf(l0 - mn);
        d0 = fmaf(d0, s, p);
        n0 = fmaf(n0, s, p * xi);
    }
    {
        float mn = fmaxf(m1, l1);
        float s = __expf(m1 - mn), p = __expf(l1 - mn);
        d1 = fmaf(d1, s, p);
        n1 = fmaf(n1, s, p * xi);
    }
    float sres0 = n0 / d0;
    float sres1 = n1 / d1;

    // fused rank-1 row write: lane ln writes float4 slots ln and ln+16
    float4 w0 = Wl4[ln],      w1 = Wl4[ln + 16];
    float4 g0 = bl4[ln],      g1 = bl4[ln + 16];
    float4 z0 = ((const float4*)bias)[ln], z1 = ((const float4*)bias)[ln + 16];
    float4* orow = out + (size_t)i * 32;
    orow[ln]      = make_float4(fmaf(sres0, w0.x, g0.x + z0.x),
                                fmaf(sres0, w0.y, g0.y + z0.y),
                                fmaf(sres0, w0.z, g0.z + z0.z),
                                fmaf(sres0, w0.w, g0.w + z0.w));
    orow[ln + 16] = make_float4(fmaf(sres1, w1.x, g1.x + z1.x),
                                fmaf(sres1, w1.y, g1.y + z1.y),
                                fmaf(sres1, w1.z, g1.z + z1.z),
                                fmaf(sres1, w1.w, g1.w + z1.w));
}

extern "C" void kernel_launch(void* const* d_in, const int* in_sizes, int n_in,
                              void* d_out, int out_size, void* d_ws, size_t ws_size,
                              hipStream_t stream) {
    const float* x    = (const float*)d_in[0];
    const int*   ei   = (const int*)  d_in[1];
    const float* attr = (const float*)d_in[2];
    const float* Wl   = (const float*)d_in[3];
    const float* bl   = (const float*)d_in[4];
    const float* Wr   = (const float*)d_in[5];
    const float* br   = (const float*)d_in[6];
    const float* We   = (const float*)d_in[7];
    const float* att  = (const float*)d_in[8];
    const float* bias = (const float*)d_in[9];
    float* out = (float*)d_out;

    const int N = in_sizes[0];       // 50000
    const int E = in_sizes[2];       // 800000
    const int* src = ei;
    const int* dst = ei + E;

    // workspace: payload [E]float4 | nxt [E]int | head [N][16]int  (~19.2 MB)
    char* w = (char*)d_ws;
    float4* payload = (float4*)w;
    int*    nxt     = (int*)(w + (size_t)E * 16);
    int*    head    = nxt + E;

    // fast head init to -1 (16N ints = 4N int4s)
    int n4 = 4 * N;
    k_fill<<<(n4 + 255) / 256, 256, 0, stream>>>((int4*)head, n4);

    int egroups = (E + 15) / 16;                    // one 16-edge chunk per group
    int eblocks = (egroups + 15) / 16;              // 16 groups per 256-thr block
    k_edge<<<eblocks, 256, 0, stream>>>(src, dst, attr, x,
                                        Wl, Wr, We, bl, br, att,
                                        head, nxt, payload, E);
    k_walk<<<((size_t)16 * N + 255) / 256, 256, 0, stream>>>(x, head, nxt, payload,
                                                             Wl, Wr, We, bl, br, att, bias,
                                                             (float4*)out, N);
}

// Round 10
// 74.296 us; speedup vs baseline: 4.7426x; 1.0681x over previous
//
#include <hip/hip_runtime.h>

#define NEG 0.2f

typedef float f4v __attribute__((ext_vector_type(4)));

__device__ __forceinline__ float leaky(float v){ return fmaxf(v, NEG * v); }

// fast -1 fill for head[] (the rocclr fillBuffer path runs at only ~67 GB/s)
__global__ void __launch_bounds__(256) k_fill(int4* __restrict__ p, int n4){
    int t = blockIdx.x * 256 + threadIdx.x;
    if (t < n4) p[t] = make_int4(-1, -1, -1, -1);
}

// ---------------------------------------------------------------------------
// k_edge: 16-lane groups, 16 edges per group. Lane ln owns channels
// ln*8..ln*8+7 (weights in VGPRs) and edge base+ln for all memory traffic:
// coalesced src/dst/attr/x loads, 16 atomicExch in flight, coalesced 32B
// record stores. Record rec[e] = {xs, a, l0, l1, nxt, 0, 0, 0} so the walk
// kernel fetches ONE 64B sector per hop. No nontemporal hints: records stay
// L2/L3-resident for k_walk.
// ---------------------------------------------------------------------------
__global__ void __launch_bounds__(256, 6) k_edge(
        const int* __restrict__ src, const int* __restrict__ dst,
        const float* __restrict__ attr, const float* __restrict__ x,
        const float* __restrict__ Wl, const float* __restrict__ Wr,
        const float* __restrict__ We, const float* __restrict__ bl,
        const float* __restrict__ br, const float* __restrict__ att,
        int* __restrict__ head, float4* __restrict__ rec, int E){
    const int ln = threadIdx.x & 15;               // channel group 0..15
    const float4* Wl4 = (const float4*)Wl;
    const float4* Wr4 = (const float4*)Wr;
    const float4* We4 = (const float4*)We;
    const float4* bl4 = (const float4*)bl;
    const float4* br4 = (const float4*)br;
    const float4* at4 = (const float4*)att;
    const int q = ln * 2;
    float4 wl0 = Wl4[q], wl1 = Wl4[q+1];
    float4 wr0 = Wr4[q], wr1 = Wr4[q+1];
    float4 we0 = We4[q], we1 = We4[q+1];
    float4 b0  = bl4[q], b1  = bl4[q+1];
    float4 c0  = br4[q], c1  = br4[q+1];
    float4 a0  = at4[q], a1  = at4[q+1];
    b0.x += c0.x; b0.y += c0.y; b0.z += c0.z; b0.w += c0.w;
    b1.x += c1.x; b1.y += c1.y; b1.z += c1.z; b1.w += c1.w;

    const int gid  = (blockIdx.x * 256 + threadIdx.x) >> 4;
    const int base = gid * 16;
    if (base >= E) return;

    const int eL = base + ln;
    const bool val = eL < E;
    int   sL = 0, dL = 0;
    float aL = 0.f;
    if (val){ sL = src[eL]; dL = dst[eL]; aL = attr[eL]; }   // coalesced
    float xsL = val ? x[sL] : 0.f;                           // 16 gathers in flight
    float xdL = val ? x[dL] : 0.f;
    int prevL = 0;
    if (val)                                                  // 16 atomics in flight
        prevL = atomicExch(&head[dL * 16 + ln], eL);

    const int cnt = min(16, E - base);
    float l0L = 0.f, l1L = 0.f;
    for (int j = 0; j < cnt; ++j){
        float xs = __shfl(xsL, j, 16);
        float xd = __shfl(xdL, j, 16);
        float a  = __shfl(aL,  j, 16);
        float acc;
        {
            float v0 = fmaf(xs, wl0.x, fmaf(xd, wr0.x, fmaf(a, we0.x, b0.x)));
            float v1 = fmaf(xs, wl0.y, fmaf(xd, wr0.y, fmaf(a, we0.y, b0.y)));
            float v2 = fmaf(xs, wl0.z, fmaf(xd, wr0.z, fmaf(a, we0.z, b0.z)));
            float v3 = fmaf(xs, wl0.w, fmaf(xd, wr0.w, fmaf(a, we0.w, b0.w)));
            acc  = leaky(v0) * a0.x;
            acc  = fmaf(leaky(v1), a0.y, acc);
            acc  = fmaf(leaky(v2), a0.z, acc);
            acc  = fmaf(leaky(v3), a0.w, acc);
            v0 = fmaf(xs, wl1.x, fmaf(xd, wr1.x, fmaf(a, we1.x, b1.x)));
            v1 = fmaf(xs, wl1.y, fmaf(xd, wr1.y, fmaf(a, we1.y, b1.y)));
            v2 = fmaf(xs, wl1.z, fmaf(xd, wr1.z, fmaf(a, we1.z, b1.z)));
            v3 = fmaf(xs, wl1.w, fmaf(xd, wr1.w, fmaf(a, we1.w, b1.w)));
            acc  = fmaf(leaky(v0), a1.x, acc);
            acc  = fmaf(leaky(v1), a1.y, acc);
            acc  = fmaf(leaky(v2), a1.z, acc);
            acc  = fmaf(leaky(v3), a1.w, acc);
        }
        // lanes 0-7 -> head0 sum, lanes 8-15 -> head1 sum; then swap halves
        acc += __shfl_xor(acc, 1);
        acc += __shfl_xor(acc, 2);
        acc += __shfl_xor(acc, 4);
        float other = __shfl_xor(acc, 8);
        if (ln == j){
            l0L = (j < 8) ? acc : other;
            l1L = (j < 8) ? other : acc;
        }
    }
    if (val){
        size_t r = 2 * (size_t)eL;
        rec[r]     = make_float4(xsL, aL, l0L, l1L);
        rec[r + 1] = make_float4(__int_as_float(prevL), 0.f, 0.f, 0.f);
    }
}

// ---------------------------------------------------------------------------
// k_walk: 16 lanes per node; lane ln walks sub-chain ln (avg length 1) with
// exact online softmax (one 64B-sector record per hop); butterfly merge;
// self-loop logit with register weights; fused rank-1 row write.
// head is node-major [N][16] -> coalesced.
// ---------------------------------------------------------------------------
__global__ void __launch_bounds__(256, 6) k_walk(
        const float* __restrict__ x,
        const int* __restrict__ head, const float4* __restrict__ rec,
        const float* __restrict__ Wl, const float* __restrict__ Wr,
        const float* __restrict__ We, const float* __restrict__ bl,
        const float* __restrict__ br, const float* __restrict__ att,
        const float* __restrict__ bias,
        float4* __restrict__ out, int N){
    int t = blockIdx.x * 256 + threadIdx.x;
    int i = t >> 4, ln = t & 15;
    if (i >= N) return;

    const float4* Wl4 = (const float4*)Wl;
    const float4* Wr4 = (const float4*)Wr;
    const float4* We4 = (const float4*)We;
    const float4* bl4 = (const float4*)bl;
    const float4* br4 = (const float4*)br;
    const float4* at4 = (const float4*)att;
    const int q = ln * 2;
    float4 wl0 = Wl4[q], wl1 = Wl4[q+1];
    float4 wr0 = Wr4[q], wr1 = Wr4[q+1];
    float4 we0 = We4[q], we1 = We4[q+1];
    float4 b0  = bl4[q], b1  = bl4[q+1];
    float4 c0  = br4[q], c1  = br4[q+1];
    float4 a0  = at4[q], a1  = at4[q+1];
    wl0.x += wr0.x; wl0.y += wr0.y; wl0.z += wr0.z; wl0.w += wr0.w;
    wl1.x += wr1.x; wl1.y += wr1.y; wl1.z += wr1.z; wl1.w += wr1.w;
    b0.x += c0.x; b0.y += c0.y; b0.z += c0.z; b0.w += c0.w;
    b1.x += c1.x; b1.y += c1.y; b1.z += c1.z; b1.w += c1.w;

    // walk this lane's sub-chain (rec pair = one 64B sector per hop)
    float m0 = -3.4e38f, d0 = 0.f, n0 = 0.f;
    float m1 = -3.4e38f, d1 = 0.f, n1 = 0.f;
    float asum = 0.f;
    int deg = 0;
    for (int e = head[(size_t)i * 16 + ln]; e >= 0; ){
        size_t r = 2 * (size_t)e;
        float4 v = rec[r];                     // (xs, a, l0, l1)
        float4 w = rec[r + 1];                 // (.x = nxt bits)
        e = __float_as_int(w.x);
        ++deg;
        asum += v.y;
        float mn0 = fmaxf(m0, v.z);
        float s0 = __expf(m0 - mn0), p0 = __expf(v.z - mn0);
        d0 = fmaf(d0, s0, p0);
        n0 = fmaf(n0, s0, p0 * v.x);
        m0 = mn0;
        float mn1 = fmaxf(m1, v.w);
        float s1 = __expf(m1 - mn1), p1 = __expf(v.w - mn1);
        d1 = fmaf(d1, s1, p1);
        n1 = fmaf(n1, s1, p1 * v.x);
        m1 = mn1;
    }
    // butterfly merge across the 16 lanes of this node
    #pragma unroll
    for (int off = 1; off < 16; off <<= 1){
        float om0 = __shfl_xor(m0, off), od0 = __shfl_xor(d0, off), on0 = __shfl_xor(n0, off);
        float om1 = __shfl_xor(m1, off), od1 = __shfl_xor(d1, off), on1 = __shfl_xor(n1, off);
        asum += __shfl_xor(asum, off);
        deg  += __shfl_xor(deg, off);
        float mn = fmaxf(m0, om0);
        d0 = d0 * __expf(m0 - mn) + od0 * __expf(om0 - mn);
        n0 = n0 * __expf(m0 - mn) + on0 * __expf(om0 - mn);
        m0 = mn;
        mn = fmaxf(m1, om1);
        d1 = d1 * __expf(m1 - mn) + od1 * __expf(om1 - mn);
        n1 = n1 * __expf(m1 - mn) + on1 * __expf(om1 - mn);
        m1 = mn;
    }
    // self-loop logit, 8 channels per lane
    float xi = x[i];
    float la = asum / (float)max(deg, 1);
    float pl;
    {
        float v0 = fmaf(xi, wl0.x, fmaf(la, we0.x, b0.x));
        float v1 = fmaf(xi, wl0.y, fmaf(la, we0.y, b0.y));
        float v2 = fmaf(xi, wl0.z, fmaf(la, we0.z, b0.z));
        float v3 = fmaf(xi, wl0.w, fmaf(la, we0.w, b0.w));
        pl  = leaky(v0) * a0.x;
        pl  = fmaf(leaky(v1), a0.y, pl);
        pl  = fmaf(leaky(v2), a0.z, pl);
        pl  = fmaf(leaky(v3), a0.w, pl);
        v0 = fmaf(xi, wl1.x, fmaf(la, we1.x, b1.x));
        v1 = fmaf(xi, wl1.y, fmaf(la, we1.y, b1.y));
        v2 = fmaf(xi, wl1.z, fmaf(la, we1.z, b1.z));
        v3 = fmaf(xi, wl1.w, fmaf(la, we1.w, b1.w));
        pl  = fmaf(leaky(v0), a1.x, pl);
        pl  = fmaf(leaky(v1), a1.y, pl);
        pl  = fmaf(leaky(v2), a1.z, pl);
        pl  = fmaf(leaky(v3), a1.w, pl);
    }
    pl += __shfl_xor(pl, 1);
    pl += __shfl_xor(pl, 2);
    pl += __shfl_xor(pl, 4);                 // lanes 0-7: l0, lanes 8-15: l1
    float other = __shfl_xor(pl, 8);
    float l0 = (ln < 8) ? pl : other;
    float l1 = (ln < 8) ? other : pl;
    // fold self-loop into merged softmax state (all lanes redundantly)
    {
        float mn = fmaxf(m0, l0);
        float s = __expf(m0 - mn), p = __expf(l0 - mn);
        d0 = fmaf(d0, s, p);
        n0 = fmaf(n0, s, p * xi);
    }
    {
        float mn = fmaxf(m1, l1);
        float s = __expf(m1 - mn), p = __expf(l1 - mn);
        d1 = fmaf(d1, s, p);
        n1 = fmaf(n1, s, p * xi);
    }
    float sres0 = n0 / d0;
    float sres1 = n1 / d1;

    // fused rank-1 row write: lane ln writes float4 slots ln and ln+16
    float4 w0 = Wl4[ln],      w1 = Wl4[ln + 16];
    float4 g0 = bl4[ln],      g1 = bl4[ln + 16];
    float4 z0 = ((const float4*)bias)[ln], z1 = ((const float4*)bias)[ln + 16];
    float4* orow = out + (size_t)i * 32;
    orow[ln]      = make_float4(fmaf(sres0, w0.x, g0.x + z0.x),
                                fmaf(sres0, w0.y, g0.y + z0.y),
                                fmaf(sres0, w0.z, g0.z + z0.z),
                                fmaf(sres0, w0.w, g0.w + z0.w));
    orow[ln + 16] = make_float4(fmaf(sres1, w1.x, g1.x + z1.x),
                                fmaf(sres1, w1.y, g1.y + z1.y),
                                fmaf(sres1, w1.z, g1.z + z1.z),
                                fmaf(sres1, w1.w, g1.w + z1.w));
}

extern "C" void kernel_launch(void* const* d_in, const int* in_sizes, int n_in,
                              void* d_out, int out_size, void* d_ws, size_t ws_size,
                              hipStream_t stream) {
    const float* x    = (const float*)d_in[0];
    const int*   ei   = (const int*)  d_in[1];
    const float* attr = (const float*)d_in[2];
    const float* Wl   = (const float*)d_in[3];
    const float* bl   = (const float*)d_in[4];
    const float* Wr   = (const float*)d_in[5];
    const float* br   = (const float*)d_in[6];
    const float* We   = (const float*)d_in[7];
    const float* att  = (const float*)d_in[8];
    const float* bias = (const float*)d_in[9];
    float* out = (float*)d_out;

    const int N = in_sizes[0];       // 50000
    const int E = in_sizes[2];       // 800000
    const int* src = ei;
    const int* dst = ei + E;

    // workspace: rec [E][2]float4 (32B/edge) | head [N][16]int   (~28.8 MB)
    char* w = (char*)d_ws;
    float4* rec  = (float4*)w;
    int*    head = (int*)(w + (size_t)E * 32);

    // fast head init to -1 (16N ints = 4N int4s)
    int n4 = 4 * N;
    k_fill<<<(n4 + 255) / 256, 256, 0, stream>>>((int4*)head, n4);

    int egroups = (E + 15) / 16;                    // one 16-edge chunk per group
    int eblocks = (egroups + 15) / 16;              // 16 groups per 256-thr block
    k_edge<<<eblocks, 256, 0, stream>>>(src, dst, attr, x,
                                        Wl, Wr, We, bl, br, att,
                                        head, rec, E);
    k_walk<<<((size_t)16 * N + 255) / 256, 256, 0, stream>>>(x, head, rec,
                                                             Wl, Wr, We, bl, br, att, bias,
                                                             (float4*)out, N);
}

// Round 12
// 73.852 us; speedup vs baseline: 4.7711x; 1.0060x over previous
//
#include <hip/hip_runtime.h>

#define NEG 0.2f

typedef float f4v __attribute__((ext_vector_type(4)));

__device__ __forceinline__ float leaky(float v){ return fmaxf(v, NEG * v); }

// fast -1 fill for head[] (the rocclr fillBuffer path runs at only ~67 GB/s)
__global__ void __launch_bounds__(256) k_fill(int4* __restrict__ p, int n4){
    int t = blockIdx.x * 256 + threadIdx.x;
    if (t < n4) p[t] = make_int4(-1, -1, -1, -1);
}

// ---------------------------------------------------------------------------
// k_edge: 16-lane groups, 16 edges per group. Lane ln owns channels
// ln*8..ln*8+7 (weights in VGPRs) and edge base+ln for all memory traffic:
// coalesced src/dst/attr/x loads, 16 atomicExch in flight, coalesced 32B
// record stores. Record rec[e] = {xs, a, l0, l1, nxt, 0, 0, 0} so the walk
// kernel fetches ONE 64B sector per hop. No nontemporal hints: records stay
// L2/L3-resident for k_walk.
// ---------------------------------------------------------------------------
__global__ void __launch_bounds__(256, 6) k_edge(
        const int* __restrict__ src, const int* __restrict__ dst,
        const float* __restrict__ attr, const float* __restrict__ x,
        const float* __restrict__ Wl, const float* __restrict__ Wr,
        const float* __restrict__ We, const float* __restrict__ bl,
        const float* __restrict__ br, const float* __restrict__ att,
        int* __restrict__ head, float4* __restrict__ rec, int E){
    const int ln = threadIdx.x & 15;               // channel group 0..15
    const float4* Wl4 = (const float4*)Wl;
    const float4* Wr4 = (const float4*)Wr;
    const float4* We4 = (const float4*)We;
    const float4* bl4 = (const float4*)bl;
    const float4* br4 = (const float4*)br;
    const float4* at4 = (const float4*)att;
    const int q = ln * 2;
    float4 wl0 = Wl4[q], wl1 = Wl4[q+1];
    float4 wr0 = Wr4[q], wr1 = Wr4[q+1];
    float4 we0 = We4[q], we1 = We4[q+1];
    float4 b0  = bl4[q], b1  = bl4[q+1];
    float4 c0  = br4[q], c1  = br4[q+1];
    float4 a0  = at4[q], a1  = at4[q+1];
    b0.x += c0.x; b0.y += c0.y; b0.z += c0.z; b0.w += c0.w;
    b1.x += c1.x; b1.y += c1.y; b1.z += c1.z; b1.w += c1.w;

    const int gid  = (blockIdx.x * 256 + threadIdx.x) >> 4;
    const int base = gid * 16;
    if (base >= E) return;

    const int eL = base + ln;
    const bool val = eL < E;
    int   sL = 0, dL = 0;
    float aL = 0.f;
    if (val){ sL = src[eL]; dL = dst[eL]; aL = attr[eL]; }   // coalesced
    float xsL = val ? x[sL] : 0.f;                           // 16 gathers in flight
    float xdL = val ? x[dL] : 0.f;
    int prevL = 0;
    if (val)                                                  // 16 atomics in flight
        prevL = atomicExch(&head[dL * 16 + ln], eL);

    const int cnt = min(16, E - base);
    float l0L = 0.f, l1L = 0.f;
    for (int j = 0; j < cnt; ++j){
        float xs = __shfl(xsL, j, 16);
        float xd = __shfl(xdL, j, 16);
        float a  = __shfl(aL,  j, 16);
        float acc;
        {
            float v0 = fmaf(xs, wl0.x, fmaf(xd, wr0.x, fmaf(a, we0.x, b0.x)));
            float v1 = fmaf(xs, wl0.y, fmaf(xd, wr0.y, fmaf(a, we0.y, b0.y)));
            float v2 = fmaf(xs, wl0.z, fmaf(xd, wr0.z, fmaf(a, we0.z, b0.z)));
            float v3 = fmaf(xs, wl0.w, fmaf(xd, wr0.w, fmaf(a, we0.w, b0.w)));
            acc  = leaky(v0) * a0.x;
            acc  = fmaf(leaky(v1), a0.y, acc);
            acc  = fmaf(leaky(v2), a0.z, acc);
            acc  = fmaf(leaky(v3), a0.w, acc);
            v0 = fmaf(xs, wl1.x, fmaf(xd, wr1.x, fmaf(a, we1.x, b1.x)));
            v1 = fmaf(xs, wl1.y, fmaf(xd, wr1.y, fmaf(a, we1.y, b1.y)));
            v2 = fmaf(xs, wl1.z, fmaf(xd, wr1.z, fmaf(a, we1.z, b1.z)));
            v3 = fmaf(xs, wl1.w, fmaf(xd, wr1.w, fmaf(a, we1.w, b1.w)));
            acc  = fmaf(leaky(v0), a1.x, acc);
            acc  = fmaf(leaky(v1), a1.y, acc);
            acc  = fmaf(leaky(v2), a1.z, acc);
            acc  = fmaf(leaky(v3), a1.w, acc);
        }
        // lanes 0-7 -> head0 sum, lanes 8-15 -> head1 sum; then swap halves
        acc += __shfl_xor(acc, 1);
        acc += __shfl_xor(acc, 2);
        acc += __shfl_xor(acc, 4);
        float other = __shfl_xor(acc, 8);
        if (ln == j){
            l0L = (j < 8) ? acc : other;
            l1L = (j < 8) ? other : acc;
        }
    }
    if (val){
        size_t r = 2 * (size_t)eL;
        rec[r]     = make_float4(xsL, aL, l0L, l1L);
        rec[r + 1] = make_float4(__int_as_float(prevL), 0.f, 0.f, 0.f);
    }
}

// ---------------------------------------------------------------------------
// k_walk: 16 lanes per node; lane ln walks sub-chain ln (avg length 1) with
// exact online softmax (one 64B-sector record per hop); butterfly merge;
// self-loop logit with register weights; fused rank-1 row write.
// head is node-major [N][16] -> coalesced.
// ---------------------------------------------------------------------------
__global__ void __launch_bounds__(256, 6) k_walk(
        const float* __restrict__ x,
        const int* __restrict__ head, const float4* __restrict__ rec,
        const float* __restrict__ Wl, const float* __restrict__ Wr,
        const float* __restrict__ We, const float* __restrict__ bl,
        const float* __restrict__ br, const float* __restrict__ att,
        const float* __restrict__ bias,
        float4* __restrict__ out, int N){
    int t = blockIdx.x * 256 + threadIdx.x;
    int i = t >> 4, ln = t & 15;
    if (i >= N) return;

    const float4* Wl4 = (const float4*)Wl;
    const float4* Wr4 = (const float4*)Wr;
    const float4* We4 = (const float4*)We;
    const float4* bl4 = (const float4*)bl;
    const float4* br4 = (const float4*)br;
    const float4* at4 = (const float4*)att;
    const int q = ln * 2;
    float4 wl0 = Wl4[q], wl1 = Wl4[q+1];
    float4 wr0 = Wr4[q], wr1 = Wr4[q+1];
    float4 we0 = We4[q], we1 = We4[q+1];
    float4 b0  = bl4[q], b1  = bl4[q+1];
    float4 c0  = br4[q], c1  = br4[q+1];
    float4 a0  = at4[q], a1  = at4[q+1];
    wl0.x += wr0.x; wl0.y += wr0.y; wl0.z += wr0.z; wl0.w += wr0.w;
    wl1.x += wr1.x; wl1.y += wr1.y; wl1.z += wr1.z; wl1.w += wr1.w;
    b0.x += c0.x; b0.y += c0.y; b0.z += c0.z; b0.w += c0.w;
    b1.x += c1.x; b1.y += c1.y; b1.z += c1.z; b1.w += c1.w;

    // walk this lane's sub-chain (rec pair = one 64B sector per hop)
    float m0 = -3.4e38f, d0 = 0.f, n0 = 0.f;
    float m1 = -3.4e38f, d1 = 0.f, n1 = 0.f;
    float asum = 0.f;
    int deg = 0;
    for (int e = head[(size_t)i * 16 + ln]; e >= 0; ){
        size_t r = 2 * (size_t)e;
        float4 v = rec[r];                     // (xs, a, l0, l1)
        float4 w = rec[r + 1];                 // (.x = nxt bits)
        e = __float_as_int(w.x);
        ++deg;
        asum += v.y;
        float mn0 = fmaxf(m0, v.z);
        float s0 = __expf(m0 - mn0), p0 = __expf(v.z - mn0);
        d0 = fmaf(d0, s0, p0);
        n0 = fmaf(n0, s0, p0 * v.x);
        m0 = mn0;
        float mn1 = fmaxf(m1, v.w);
        float s1 = __expf(m1 - mn1), p1 = __expf(v.w - mn1);
        d1 = fmaf(d1, s1, p1);
        n1 = fmaf(n1, s1, p1 * v.x);
        m1 = mn1;
    }
    // butterfly merge across the 16 lanes of this node
    #pragma unroll
    for (int off = 1; off < 16; off <<= 1){
        float om0 = __shfl_xor(m0, off), od0 = __shfl_xor(d0, off), on0 = __shfl_xor(n0, off);
        float om1 = __shfl_xor(m1, off), od1 = __shfl_xor(d1, off), on1 = __shfl_xor(n1, off);
        asum += __shfl_xor(asum, off);
        deg  += __shfl_xor(deg, off);
        float mn = fmaxf(m0, om0);
        d0 = d0 * __expf(m0 - mn) + od0 * __expf(om0 - mn);
        n0 = n0 * __expf(m0 - mn) + on0 * __expf(om0 - mn);
        m0 = mn;
        mn = fmaxf(m1, om1);
        d1 = d1 * __expf(m1 - mn) + od1 * __expf(om1 - mn);
        n1 = n1 * __expf(m1 - mn) + on1 * __expf(om1 - mn);
        m1 = mn;
    }
    // self-loop logit, 8 channels per lane
    float xi = x[i];
    float la = asum / (float)max(deg, 1);
    float pl;
    {
        float v0 = fmaf(xi, wl0.x, fmaf(la, we0.x, b0.x));
        float v1 = fmaf(xi, wl0.y, fmaf(la, we0.y, b0.y));
        float v2 = fmaf(xi, wl0.z, fmaf(la, we0.z, b0.z));
        float v3 = fmaf(xi, wl0.w, fmaf(la, we0.w, b0.w));
        pl  = leaky(v0) * a0.x;
        pl  = fmaf(leaky(v1), a0.y, pl);
        pl  = fmaf(leaky(v2), a0.z, pl);
        pl  = fmaf(leaky(v3), a0.w, pl);
        v0 = fmaf(xi, wl1.x, fmaf(la, we1.x, b1.x));
        v1 = fmaf(xi, wl1.y, fmaf(la, we1.y, b1.y));
        v2 = fmaf(xi, wl1.z, fmaf(la, we1.z, b1.z));
        v3 = fmaf(xi, wl1.w, fmaf(la, we1.w, b1.w));
        pl  = fmaf(leaky(v0), a1.x, pl);
        pl  = fmaf(leaky(v1), a1.y, pl);
        pl  = fmaf(leaky(v2), a1.z, pl);
        pl  = fmaf(leaky(v3), a1.w, pl);
    }
    pl += __shfl_xor(pl, 1);
    pl += __shfl_xor(pl, 2);
    pl += __shfl_xor(pl, 4);                 // lanes 0-7: l0, lanes 8-15: l1
    float other = __shfl_xor(pl, 8);
    float l0 = (ln < 8) ? pl : other;
    float l1 = (ln < 8) ? other : pl;
    // fold self-loop into merged softmax state (all lanes redundantly)
    {
        float mn = fmaxf(m0, l0);
        float s = __expf(m0 - mn), p = __expf(l0 - mn);
        d0 = fmaf(d0, s, p);
        n0 = fmaf(n0, s, p * xi);
    }
    {
        float mn = fmaxf(m1, l1);
        float s = __expf(m1 - mn), p = __expf(l1 - mn);
        d1 = fmaf(d1, s, p);
        n1 = fmaf(n1, s, p * xi);
    }
    float sres0 = n0 / d0;
    float sres1 = n1 / d1;

    // fused rank-1 row write: lane ln writes float4 slots ln and ln+16
    float4 w0 = Wl4[ln],      w1 = Wl4[ln + 16];
    float4 g0 = bl4[ln],      g1 = bl4[ln + 16];
    float4 z0 = ((const float4*)bias)[ln], z1 = ((const float4*)bias)[ln + 16];
    float4* orow = out + (size_t)i * 32;
    orow[ln]      = make_float4(fmaf(sres0, w0.x, g0.x + z0.x),
                                fmaf(sres0, w0.y, g0.y + z0.y),
                                fmaf(sres0, w0.z, g0.z + z0.z),
                                fmaf(sres0, w0.w, g0.w + z0.w));
    orow[ln + 16] = make_float4(fmaf(sres1, w1.x, g1.x + z1.x),
                                fmaf(sres1, w1.y, g1.y + z1.y),
                                fmaf(sres1, w1.z, g1.z + z1.z),
                                fmaf(sres1, w1.w, g1.w + z1.w));
}

extern "C" void kernel_launch(void* const* d_in, const int* in_sizes, int n_in,
                              void* d_out, int out_size, void* d_ws, size_t ws_size,
                              hipStream_t stream) {
    const float* x    = (const float*)d_in[0];
    const int*   ei   = (const int*)  d_in[1];
    const float* attr = (const float*)d_in[2];
    const float* Wl   = (const float*)d_in[3];
    const float* bl   = (const float*)d_in[4];
    const float* Wr   = (const float*)d_in[5];
    const float* br   = (const float*)d_in[6];
    const float* We   = (const float*)d_in[7];
    const float* att  = (const float*)d_in[8];
    const float* bias = (const float*)d_in[9];
    float* out = (float*)d_out;

    const int N = in_sizes[0];       // 50000
    const int E = in_sizes[2];       // 800000
    const int* src = ei;
    const int* dst = ei + E;

    // workspace: rec [E][2]float4 (32B/edge) | head [N][16]int   (~28.8 MB)
    char* w = (char*)d_ws;
    float4* rec  = (float4*)w;
    int*    head = (int*)(w + (size_t)E * 32);

    // fast head init to -1 (16N ints = 4N int4s)
    int n4 = 4 * N;
    k_fill<<<(n4 + 255) / 256, 256, 0, stream>>>((int4*)head, n4);

    int egroups = (E + 15) / 16;                    // one 16-edge chunk per group
    int eblocks = (egroups + 15) / 16;              // 16 groups per 256-thr block
    k_edge<<<eblocks, 256, 0, stream>>>(src, dst, attr, x,
                                        Wl, Wr, We, bl, br, att,
                                        head, rec, E);
    k_walk<<<((size_t)16 * N + 255) / 256, 256, 0, stream>>>(x, head, rec,
                                                             Wl, Wr, We, bl, br, att, bias,
                                                             (float4*)out, N);
}